// Round 1
// 632.351 us; speedup vs baseline: 1.2136x; 1.2136x over previous
//
#include <hip/hip_runtime.h>

#define N_NODES 100000
#define N_EDGES 3200000
#define IN_DIM 256
#define HIDDEN 128
#define OUT_DIM 64

#define NBUCK 782        // ceil(100000 / 128) buckets of 128 dst rows
#define CHUNK 5120       // edges per partition block
#define BCAP 6144        // max edges per bucket for LDS sort (mean 4096, sd 64)

typedef unsigned int uint32;
typedef unsigned short ushort16;

typedef short short8 __attribute__((ext_vector_type(8)));   // 8 bf16 (4 VGPRs)
typedef float f32x4 __attribute__((ext_vector_type(4)));    // MFMA acc

// round-to-nearest-even f32 -> bf16
__device__ __forceinline__ ushort16 f2bf(float f) {
    uint32 u = __float_as_uint(f);
    u += 0x7fffu + ((u >> 16) & 1u);
    return (ushort16)(u >> 16);
}

// split f32 into bf16 hi + bf16 lo, f ~= hi + lo (error ~2^-16 rel)
__device__ __forceinline__ void splitbf(float f, unsigned short& hi, unsigned short& lo) {
    uint32 u = __float_as_uint(f);
    uint32 r = u + 0x7fffu + ((u >> 16) & 1u);
    hi = (unsigned short)(r >> 16);
    float hf = __uint_as_float((r >> 16) << 16);
    float res = f - hf;                    // exact (Sterbenz: same binade)
    uint32 v = __float_as_uint(res);
    lo = (unsigned short)((v + 0x7fffu + ((v >> 16) & 1u)) >> 16);
}

// ---------------- bucket histogram ----------------

__global__ __launch_bounds__(256)
void hist_bucket(const int* __restrict__ edst, int* __restrict__ bcnt, int E) {
    __shared__ int h[NBUCK];
    for (int b = threadIdx.x; b < NBUCK; b += 256) h[b] = 0;
    __syncthreads();
    for (int i = blockIdx.x * 256 + threadIdx.x; i < E; i += gridDim.x * 256)
        atomicAdd(&h[edst[i] >> 7], 1);
    __syncthreads();
    for (int b = threadIdx.x; b < NBUCK; b += 256) {
        int c = h[b];
        if (c) atomicAdd(&bcnt[b], c);
    }
}

// ---------------- bucket exclusive scan (one block) ----------------

__global__ __launch_bounds__(256)
void bucket_scan(const int* __restrict__ bcnt, int* __restrict__ bptr,
                 int* __restrict__ cursor, int* __restrict__ row_ptr, int E) {
    __shared__ int st[256];
    int tid = threadIdx.x;
    int v4[4];
    int s0 = 0;
#pragma unroll
    for (int k = 0; k < 4; k++) {
        int b = tid * 4 + k;
        v4[k] = (b < NBUCK) ? bcnt[b] : 0;
        s0 += v4[k];
    }
    st[tid] = s0;
    __syncthreads();
    for (int off = 1; off < 256; off <<= 1) {
        int t = (tid >= off) ? st[tid - off] : 0;
        __syncthreads();
        st[tid] += t;
        __syncthreads();
    }
    int run = st[tid] - s0;
#pragma unroll
    for (int k = 0; k < 4; k++) {
        int b = tid * 4 + k;
        if (b < NBUCK) { bptr[b] = run; cursor[b] = run; }
        run += v4[k];
    }
    if (tid == 255) bptr[NBUCK] = run;
    if (tid == 0) row_ptr[N_NODES] = E;
}

// ---------------- partition: LDS counting-sort per chunk ----------------
// payload p.x = src | (dst&127)<<17 ; p.y = val bits

__global__ __launch_bounds__(256)
void partition_kernel(const int* __restrict__ esrc, const int* __restrict__ edst,
                      const float* __restrict__ evals, int* __restrict__ cursor,
                      int2* __restrict__ part, int E) {
    __shared__ int hist[NBUCK];
    __shared__ int basepos[NBUCK];
    __shared__ int st[256];
    __shared__ unsigned short sbb[CHUNK];
    __shared__ int2 sbp[CHUNK];
    int tid = threadIdx.x;
    long base = (long)blockIdx.x * CHUNK;
    int cnt = (int)min((long)CHUNK, (long)E - base);

    for (int b = tid; b < NBUCK; b += 256) hist[b] = 0;
    __syncthreads();
    for (int j = tid; j < cnt; j += 256)
        atomicAdd(&hist[edst[base + j] >> 7], 1);
    __syncthreads();

    int v4[4];
    int s0 = 0;
#pragma unroll
    for (int k = 0; k < 4; k++) {
        int b = tid * 4 + k;
        v4[k] = (b < NBUCK) ? hist[b] : 0;
        s0 += v4[k];
    }
    st[tid] = s0;
    __syncthreads();
    for (int off = 1; off < 256; off <<= 1) {
        int t = (tid >= off) ? st[tid - off] : 0;
        __syncthreads();
        st[tid] += t;
        __syncthreads();
    }
    int run = st[tid] - s0;
#pragma unroll
    for (int k = 0; k < 4; k++) {
        int b = tid * 4 + k;
        if (b < NBUCK) {
            int gbase = (v4[k] > 0) ? atomicAdd(&cursor[b], v4[k]) : 0;
            basepos[b] = gbase - run;
            hist[b] = run;
        }
        run += v4[k];
    }
    __syncthreads();

    for (int j = tid; j < cnt; j += 256) {
        int d = edst[base + j];
        int b = d >> 7;
        int pos = atomicAdd(&hist[b], 1);
        sbb[pos] = (unsigned short)b;
        sbp[pos] = make_int2(esrc[base + j] | ((d & 127) << 17),
                             __float_as_int(evals[base + j]));
    }
    __syncthreads();

    for (int j = tid; j < cnt; j += 256) {
        int b = sbb[j];
        part[basepos[b] + j] = sbp[j];
    }
}

// ---------------- per-bucket counting sort -> row-sorted CSR (in place) ----------------

__global__ __launch_bounds__(256)
void bucket_to_csr(const int* __restrict__ bptr, int2* __restrict__ part,
                   int* __restrict__ row_ptr) {
    __shared__ int2 se[BCAP];
    __shared__ int rcnt[128];
    __shared__ int rcur[128];
    int tid = threadIdx.x;
    int b = blockIdx.x;
    int s = bptr[b], e = bptr[b + 1];
    int cnt = min(e - s, BCAP);

    if (tid < 128) rcnt[tid] = 0;
    __syncthreads();
    for (int j = tid; j < cnt; j += 256) {
        int2 p = part[s + j];
        se[j] = p;
        atomicAdd(&rcnt[p.x >> 17], 1);
    }
    __syncthreads();

    int v = (tid < 128) ? rcnt[tid] : 0;
    if (tid < 128) rcur[tid] = v;
    __syncthreads();
    for (int off = 1; off < 128; off <<= 1) {
        int t = 0;
        if (tid < 128 && tid >= off) t = rcur[tid - off];
        __syncthreads();
        if (tid < 128 && tid >= off) rcur[tid] += t;
        __syncthreads();
    }
    if (tid < 128) {
        int excl = rcur[tid] - v;
        rcur[tid] = excl;
        int row = b * 128 + tid;
        if (row < N_NODES) row_ptr[row] = s + excl;
    }
    __syncthreads();

    for (int j = tid; j < cnt; j += 256) {
        int2 p = se[j];
        int r = p.x >> 17;
        int pos = atomicAdd(&rcur[r], 1);
        part[s + pos] = make_int2(p.x & 0x1FFFF, p.y);
    }
}

// ---------------- weight transpose + bf16 hi/lo split (tiny, once per call) ----------------
// w1[k][n] (256x128) -> w1t_hi/lo[n][k] ; w2[k][n] (128x64) -> w2t_hi/lo[n][k]

__global__ __launch_bounds__(256)
void splitw_kernel(const float* __restrict__ w1, const float* __restrict__ w2,
                   ushort16* __restrict__ w1t_hi, ushort16* __restrict__ w1t_lo,
                   ushort16* __restrict__ w2t_hi, ushort16* __restrict__ w2t_lo) {
    int g = blockIdx.x * 256 + threadIdx.x;
    if (g < IN_DIM * HIDDEN) {
        int k = g / HIDDEN, n = g % HIDDEN;
        unsigned short h, l;
        splitbf(w1[g], h, l);
        w1t_hi[n * IN_DIM + k] = h;
        w1t_lo[n * IN_DIM + k] = l;
    } else {
        int g2 = g - IN_DIM * HIDDEN;
        if (g2 < HIDDEN * OUT_DIM) {
            int k = g2 / OUT_DIM, n = g2 % OUT_DIM;
            unsigned short h, l;
            splitbf(w2[g2], h, l);
            w2t_hi[n * HIDDEN + k] = h;
            w2t_lo[n * HIDDEN + k] = l;
        }
    }
}

// ---------------- MFMA GEMM: C(bf16) = A(fp32) @ B, split-bf16 3-product ----------------
// A: [M][K] fp32, staged to LDS as bf16 hi/lo with XOR swizzle (G4).
// Bt_hi/lo: [BN][K] bf16 (pre-transposed weights), fragments loaded direct from L2.
// acc += ah*bh + ah*bl + al*bh  (drops al*bl ~ 2^-16 rel -> ~fp32 accuracy).
// 4 waves in 2x2; each wave computes 64 x (BN/2) via 16x16x32 fragments.
// Fragment layouts per guide §3 (m89-verified):
//   A/B operand: idx = lane&15 (row/col), k = (lane>>4)*8 + j  (contiguous 8 -> ds_read_b128)
//   C/D:         col = lane&15, row = (lane>>4)*4 + reg

template <int K, int BN>
__launch_bounds__(256)
__global__ void gemm_mfma(const float* __restrict__ A,
                          const ushort16* __restrict__ Bt_hi,
                          const ushort16* __restrict__ Bt_lo,
                          ushort16* __restrict__ C, int M) {
    constexpr int BM = 128, BK = 64;
    constexpr int NF = BN / 32;              // n-frags per wave (wave n-span = BN/2)
    __shared__ __align__(16) unsigned short Ah[BM * BK];
    __shared__ __align__(16) unsigned short Al[BM * BK];

    int tid = threadIdx.x;
    int wid = tid >> 6, lane = tid & 63;
    int wr = wid >> 1, wc = wid & 1;         // wave row/col in 2x2
    int rowBase = blockIdx.x * BM;
    int r = lane & 15, kg = lane >> 4;       // frag row(col) index, k-group
    int swzmask = (lane & 7) << 4;           // == (r&7)<<4; rows hit 8 distinct 16B slots

    f32x4 zero = {0.f, 0.f, 0.f, 0.f};
    f32x4 acc[4][NF];
#pragma unroll
    for (int m = 0; m < 4; m++)
#pragma unroll
        for (int n = 0; n < NF; n++) acc[m][n] = zero;

    // staging: thread t covers k4=(t&15)*4, rows (t>>4)+16i  -> coalesced float4 global loads
    int sk4 = (tid & 15) * 4;
    int sm0 = tid >> 4;

    for (int k0 = 0; k0 < K; k0 += BK) {
#pragma unroll
        for (int i = 0; i < 8; i++) {
            int m = sm0 + i * 16;
            int row = rowBase + m;
            float4 f = make_float4(0.f, 0.f, 0.f, 0.f);
            if (row < M) f = *(const float4*)(A + (size_t)row * K + k0 + sk4);
            ushort4 h, l;
            splitbf(f.x, h.x, l.x);
            splitbf(f.y, h.y, l.y);
            splitbf(f.z, h.z, l.z);
            splitbf(f.w, h.w, l.w);
            int bo = (m * BK + sk4) * 2;
            int swz = bo ^ ((m & 7) << 4);
            *(ushort4*)((char*)Ah + swz) = h;
            *(ushort4*)((char*)Al + swz) = l;
        }
        __syncthreads();

#pragma unroll
        for (int kk = 0; kk < BK / 32; kk++) {
            // A fragments from LDS (swizzled ds_read_b128, hi+lo)
            short8 ah[4], al[4];
            int abase = (wr * 64 + r) * (BK * 2) + kk * 64 + kg * 16;
#pragma unroll
            for (int m = 0; m < 4; m++) {
                int swz = (abase + m * (16 * BK * 2)) ^ swzmask;
                ah[m] = *(const short8*)((const char*)Ah + swz);
                al[m] = *(const short8*)((const char*)Al + swz);
            }
            // B fragments direct from global (L2-resident weights)
            short8 bh[NF], bl[NF];
#pragma unroll
            for (int n = 0; n < NF; n++) {
                size_t off = (size_t)(wc * (BN / 2) + n * 16 + r) * K + k0 + kk * 32 + kg * 8;
                bh[n] = *(const short8*)(Bt_hi + off);
                bl[n] = *(const short8*)(Bt_lo + off);
            }
#pragma unroll
            for (int m = 0; m < 4; m++)
#pragma unroll
                for (int n = 0; n < NF; n++) {
                    acc[m][n] = __builtin_amdgcn_mfma_f32_16x16x32_bf16(ah[m], bh[n], acc[m][n], 0, 0, 0);
                    acc[m][n] = __builtin_amdgcn_mfma_f32_16x16x32_bf16(ah[m], bl[n], acc[m][n], 0, 0, 0);
                    acc[m][n] = __builtin_amdgcn_mfma_f32_16x16x32_bf16(al[m], bh[n], acc[m][n], 0, 0, 0);
                }
        }
        __syncthreads();
    }

    // epilogue: bf16 store (C/D layout: col=lane&15, row=(lane>>4)*4+reg)
#pragma unroll
    for (int m = 0; m < 4; m++) {
        int row0 = rowBase + wr * 64 + m * 16 + kg * 4;
#pragma unroll
        for (int j = 0; j < 4; j++) {
            int row = row0 + j;
            if (row < M) {
#pragma unroll
                for (int n = 0; n < NF; n++) {
                    int col = wc * (BN / 2) + n * 16 + r;
                    C[(size_t)row * BN + col] = f2bf(acc[m][n][j]);
                }
            }
        }
    }
}

// ---------------- SpMM: wave per dst row, bf16 features, fp32 accumulate ----------------

template <int D, bool RELU>
__launch_bounds__(256)
__global__ void spmm_kernel(const ushort16* __restrict__ feat, const int2* __restrict__ csr_pair,
                            const int* __restrict__ row_ptr, float* __restrict__ out, int n) {
    int wid = threadIdx.x >> 6;
    int lane = threadIdx.x & 63;
    int row = blockIdx.x * 4 + wid;
    if (row >= n) return;
    int s = row_ptr[row], e = row_ptr[row + 1];

    if (D == 128) {
        float ax[8], ay[8];
#pragma unroll
        for (int k = 0; k < 8; k++) { ax[k] = 0.f; ay[k] = 0.f; }
        int i = s;
        for (; i + 8 <= e; i += 8) {
            int2 p[8];
            uint32 u[8];
#pragma unroll
            for (int k = 0; k < 8; k++) p[k] = csr_pair[i + k];
#pragma unroll
            for (int k = 0; k < 8; k++)
                u[k] = *(const uint32*)(feat + (size_t)p[k].x * 128 + lane * 2);
#pragma unroll
            for (int k = 0; k < 8; k++) {
                float v = __int_as_float(p[k].y);
                ax[k] += v * __uint_as_float(u[k] << 16);
                ay[k] += v * __uint_as_float(u[k] & 0xffff0000u);
            }
        }
        for (; i < e; i++) {
            int2 p = csr_pair[i];
            uint32 u = *(const uint32*)(feat + (size_t)p.x * 128 + lane * 2);
            float v = __int_as_float(p.y);
            ax[0] += v * __uint_as_float(u << 16);
            ay[0] += v * __uint_as_float(u & 0xffff0000u);
        }
        float sx = ((ax[0] + ax[1]) + (ax[2] + ax[3])) + ((ax[4] + ax[5]) + (ax[6] + ax[7]));
        float sy = ((ay[0] + ay[1]) + (ay[2] + ay[3])) + ((ay[4] + ay[5]) + (ay[6] + ay[7]));
        if (RELU) {
            sx = sx > 0.f ? sx : 0.f;
            sy = sy > 0.f ? sy : 0.f;
        }
        *reinterpret_cast<float2*>(out + (size_t)row * 128 + lane * 2) = make_float2(sx, sy);
    } else {
        float a[8];
#pragma unroll
        for (int k = 0; k < 8; k++) a[k] = 0.f;
        int i = s;
        for (; i + 8 <= e; i += 8) {
            int2 p[8];
            ushort16 us[8];
#pragma unroll
            for (int k = 0; k < 8; k++) p[k] = csr_pair[i + k];
#pragma unroll
            for (int k = 0; k < 8; k++) us[k] = feat[(size_t)p[k].x * D + lane];
#pragma unroll
            for (int k = 0; k < 8; k++)
                a[k] += __int_as_float(p[k].y) * __uint_as_float((uint32)us[k] << 16);
        }
        for (; i < e; i++) {
            int2 p = csr_pair[i];
            a[0] += __int_as_float(p.y) * __uint_as_float((uint32)feat[(size_t)p.x * D + lane] << 16);
        }
        float sa = ((a[0] + a[1]) + (a[2] + a[3])) + ((a[4] + a[5]) + (a[6] + a[7]));
        if (RELU) sa = sa > 0.f ? sa : 0.f;
        out[(size_t)row * D + lane] = sa;
    }
}

// ---------------- launch ----------------

extern "C" void kernel_launch(void* const* d_in, const int* in_sizes, int n_in,
                              void* d_out, int out_size, void* d_ws, size_t ws_size,
                              hipStream_t stream) {
    const float* x    = (const float*)d_in[0];
    const float* adj  = (const float*)d_in[1];
    const float* w1   = (const float*)d_in[2];
    const float* w2   = (const float*)d_in[3];
    const int*   esrc = (const int*)d_in[4];
    const int*   edst = (const int*)d_in[5];
    float* out = (float*)d_out;

    const int N = N_NODES;
    const int E = N_EDGES;

    char* ws = (char*)d_ws;
    size_t off = 0;
    auto take = [&](size_t bytes) -> char* {
        char* p = ws + off;
        off = (off + bytes + 255) & ~(size_t)255;
        return p;
    };
    int*      bcnt    = (int*)take((size_t)NBUCK * 4);
    int*      bptr    = (int*)take((size_t)(NBUCK + 1) * 4);
    int*      cursor  = (int*)take((size_t)NBUCK * 4);
    int*      row_ptr = (int*)take((size_t)(N + 1) * 4);
    int2*     part    = (int2*)take((size_t)E * 8);          // becomes row-sorted CSR
    ushort16* pre1    = (ushort16*)take((size_t)N * HIDDEN * 2);   // bf16
    ushort16* pre2    = (ushort16*)take((size_t)N * OUT_DIM * 2);  // bf16
    float*    h       = (float*)take((size_t)N * HIDDEN * 4);      // fp32
    ushort16* w1t_hi  = (ushort16*)take((size_t)HIDDEN * IN_DIM * 2);
    ushort16* w1t_lo  = (ushort16*)take((size_t)HIDDEN * IN_DIM * 2);
    ushort16* w2t_hi  = (ushort16*)take((size_t)OUT_DIM * HIDDEN * 2);
    ushort16* w2t_lo  = (ushort16*)take((size_t)OUT_DIM * HIDDEN * 2);

    // weight transpose + split (tiny)
    splitw_kernel<<<(IN_DIM * HIDDEN + HIDDEN * OUT_DIM + 255) / 256, 256, 0, stream>>>(
        w1, w2, w1t_hi, w1t_lo, w2t_hi, w2t_lo);

    // CSR build: bucket partition -> per-bucket counting sort
    hipMemsetAsync(bcnt, 0, (size_t)NBUCK * 4, stream);
    hist_bucket<<<1024, 256, 0, stream>>>(edst, bcnt, E);
    bucket_scan<<<1, 256, 0, stream>>>(bcnt, bptr, cursor, row_ptr, E);
    partition_kernel<<<(E + CHUNK - 1) / CHUNK, 256, 0, stream>>>(esrc, edst, adj, cursor, part, E);
    bucket_to_csr<<<NBUCK, 256, 0, stream>>>(bptr, part, row_ptr);

    // Layer 1: pre1 = bf16(X@W1) via MFMA ; h = relu(A @ pre1) in fp32
    gemm_mfma<IN_DIM, HIDDEN><<<(N + 127) / 128, 256, 0, stream>>>(x, w1t_hi, w1t_lo, pre1, N);
    spmm_kernel<HIDDEN, true><<<(N + 3) / 4, 256, 0, stream>>>(pre1, part, row_ptr, h, N);

    // Layer 2: pre2 = bf16(h@W2) via MFMA ; out = A @ pre2 in fp32
    gemm_mfma<HIDDEN, OUT_DIM><<<(N + 127) / 128, 256, 0, stream>>>(h, w2t_hi, w2t_lo, pre2, N);
    spmm_kernel<OUT_DIM, false><<<(N + 3) / 4, 256, 0, stream>>>(pre2, part, row_ptr, out, N);
}

// Round 2
// 579.435 us; speedup vs baseline: 1.3244x; 1.0913x over previous
//
#include <hip/hip_runtime.h>

#define N_NODES 100000
#define N_EDGES 3200000
#define IN_DIM 256
#define HIDDEN 128
#define OUT_DIM 64

#define NBUCK 782        // ceil(100000 / 128) buckets of 128 dst rows
#define CHUNK 5120       // edges per partition block
#define BCAP 6144        // max edges per bucket for LDS sort (mean 4096, sd 64)

typedef unsigned int uint32;
typedef unsigned short ushort16;

typedef short short8 __attribute__((ext_vector_type(8)));   // 8 bf16 (4 VGPRs)
typedef float f32x4 __attribute__((ext_vector_type(4)));    // MFMA acc

// round-to-nearest-even f32 -> bf16
__device__ __forceinline__ ushort16 f2bf(float f) {
    uint32 u = __float_as_uint(f);
    u += 0x7fffu + ((u >> 16) & 1u);
    return (ushort16)(u >> 16);
}

// split f32 into bf16 hi + bf16 lo, f ~= hi + lo (error ~2^-16 rel)
__device__ __forceinline__ void splitbf(float f, unsigned short& hi, unsigned short& lo) {
    uint32 u = __float_as_uint(f);
    uint32 r = u + 0x7fffu + ((u >> 16) & 1u);
    hi = (unsigned short)(r >> 16);
    float hf = __uint_as_float((r >> 16) << 16);
    float res = f - hf;                    // exact (Sterbenz: same binade)
    uint32 v = __float_as_uint(res);
    lo = (unsigned short)((v + 0x7fffu + ((v >> 16) & 1u)) >> 16);
}

// ---------------- bucket histogram ----------------

__global__ __launch_bounds__(256)
void hist_bucket(const int* __restrict__ edst, int* __restrict__ bcnt, int E) {
    __shared__ int h[NBUCK];
    for (int b = threadIdx.x; b < NBUCK; b += 256) h[b] = 0;
    __syncthreads();
    for (int i = blockIdx.x * 256 + threadIdx.x; i < E; i += gridDim.x * 256)
        atomicAdd(&h[edst[i] >> 7], 1);
    __syncthreads();
    for (int b = threadIdx.x; b < NBUCK; b += 256) {
        int c = h[b];
        if (c) atomicAdd(&bcnt[b], c);
    }
}

// ---------------- bucket exclusive scan (one block) ----------------

__global__ __launch_bounds__(256)
void bucket_scan(const int* __restrict__ bcnt, int* __restrict__ bptr,
                 int* __restrict__ cursor, int* __restrict__ row_ptr, int E) {
    __shared__ int st[256];
    int tid = threadIdx.x;
    int v4[4];
    int s0 = 0;
#pragma unroll
    for (int k = 0; k < 4; k++) {
        int b = tid * 4 + k;
        v4[k] = (b < NBUCK) ? bcnt[b] : 0;
        s0 += v4[k];
    }
    st[tid] = s0;
    __syncthreads();
    for (int off = 1; off < 256; off <<= 1) {
        int t = (tid >= off) ? st[tid - off] : 0;
        __syncthreads();
        st[tid] += t;
        __syncthreads();
    }
    int run = st[tid] - s0;
#pragma unroll
    for (int k = 0; k < 4; k++) {
        int b = tid * 4 + k;
        if (b < NBUCK) { bptr[b] = run; cursor[b] = run; }
        run += v4[k];
    }
    if (tid == 255) bptr[NBUCK] = run;
    if (tid == 0) row_ptr[N_NODES] = E;
}

// ---------------- partition: LDS counting-sort per chunk ----------------
// payload p.x = src | (dst&127)<<17 ; p.y = val bits

__global__ __launch_bounds__(256)
void partition_kernel(const int* __restrict__ esrc, const int* __restrict__ edst,
                      const float* __restrict__ evals, int* __restrict__ cursor,
                      int2* __restrict__ part, int E) {
    __shared__ int hist[NBUCK];
    __shared__ int basepos[NBUCK];
    __shared__ int st[256];
    __shared__ unsigned short sbb[CHUNK];
    __shared__ int2 sbp[CHUNK];
    int tid = threadIdx.x;
    long base = (long)blockIdx.x * CHUNK;
    int cnt = (int)min((long)CHUNK, (long)E - base);

    for (int b = tid; b < NBUCK; b += 256) hist[b] = 0;
    __syncthreads();
    for (int j = tid; j < cnt; j += 256)
        atomicAdd(&hist[edst[base + j] >> 7], 1);
    __syncthreads();

    int v4[4];
    int s0 = 0;
#pragma unroll
    for (int k = 0; k < 4; k++) {
        int b = tid * 4 + k;
        v4[k] = (b < NBUCK) ? hist[b] : 0;
        s0 += v4[k];
    }
    st[tid] = s0;
    __syncthreads();
    for (int off = 1; off < 256; off <<= 1) {
        int t = (tid >= off) ? st[tid - off] : 0;
        __syncthreads();
        st[tid] += t;
        __syncthreads();
    }
    int run = st[tid] - s0;
#pragma unroll
    for (int k = 0; k < 4; k++) {
        int b = tid * 4 + k;
        if (b < NBUCK) {
            int gbase = (v4[k] > 0) ? atomicAdd(&cursor[b], v4[k]) : 0;
            basepos[b] = gbase - run;
            hist[b] = run;
        }
        run += v4[k];
    }
    __syncthreads();

    for (int j = tid; j < cnt; j += 256) {
        int d = edst[base + j];
        int b = d >> 7;
        int pos = atomicAdd(&hist[b], 1);
        sbb[pos] = (unsigned short)b;
        sbp[pos] = make_int2(esrc[base + j] | ((d & 127) << 17),
                             __float_as_int(evals[base + j]));
    }
    __syncthreads();

    for (int j = tid; j < cnt; j += 256) {
        int b = sbb[j];
        part[basepos[b] + j] = sbp[j];
    }
}

// ---------------- per-bucket counting sort -> row-sorted CSR (in place) ----------------

__global__ __launch_bounds__(256)
void bucket_to_csr(const int* __restrict__ bptr, int2* __restrict__ part,
                   int* __restrict__ row_ptr) {
    __shared__ int2 se[BCAP];
    __shared__ int rcnt[128];
    __shared__ int rcur[128];
    int tid = threadIdx.x;
    int b = blockIdx.x;
    int s = bptr[b], e = bptr[b + 1];
    int cnt = min(e - s, BCAP);

    if (tid < 128) rcnt[tid] = 0;
    __syncthreads();
    for (int j = tid; j < cnt; j += 256) {
        int2 p = part[s + j];
        se[j] = p;
        atomicAdd(&rcnt[p.x >> 17], 1);
    }
    __syncthreads();

    int v = (tid < 128) ? rcnt[tid] : 0;
    if (tid < 128) rcur[tid] = v;
    __syncthreads();
    for (int off = 1; off < 128; off <<= 1) {
        int t = 0;
        if (tid < 128 && tid >= off) t = rcur[tid - off];
        __syncthreads();
        if (tid < 128 && tid >= off) rcur[tid] += t;
        __syncthreads();
    }
    if (tid < 128) {
        int excl = rcur[tid] - v;
        rcur[tid] = excl;
        int row = b * 128 + tid;
        if (row < N_NODES) row_ptr[row] = s + excl;
    }
    __syncthreads();

    for (int j = tid; j < cnt; j += 256) {
        int2 p = se[j];
        int r = p.x >> 17;
        int pos = atomicAdd(&rcur[r], 1);
        part[s + pos] = make_int2(p.x & 0x1FFFF, p.y);
    }
}

// ---------------- weight transpose + bf16 hi/lo split (tiny, once per call) ----------------
// w1[k][n] (256x128) -> w1t_hi/lo[n][k] ; w2[k][n] (128x64) -> w2t_hi/lo[n][k]

__global__ __launch_bounds__(256)
void splitw_kernel(const float* __restrict__ w1, const float* __restrict__ w2,
                   ushort16* __restrict__ w1t_hi, ushort16* __restrict__ w1t_lo,
                   ushort16* __restrict__ w2t_hi, ushort16* __restrict__ w2t_lo) {
    int g = blockIdx.x * 256 + threadIdx.x;
    if (g < IN_DIM * HIDDEN) {
        int k = g / HIDDEN, n = g % HIDDEN;
        unsigned short h, l;
        splitbf(w1[g], h, l);
        w1t_hi[n * IN_DIM + k] = h;
        w1t_lo[n * IN_DIM + k] = l;
    } else {
        int g2 = g - IN_DIM * HIDDEN;
        if (g2 < HIDDEN * OUT_DIM) {
            int k = g2 / OUT_DIM, n = g2 % OUT_DIM;
            unsigned short h, l;
            splitbf(w2[g2], h, l);
            w2t_hi[n * HIDDEN + k] = h;
            w2t_lo[n * HIDDEN + k] = l;
        }
    }
}

// ---------------- MFMA GEMM: C(bf16) = A(fp32) @ B, split-bf16 3-product ----------------

template <int K, int BN>
__launch_bounds__(256)
__global__ void gemm_mfma(const float* __restrict__ A,
                          const ushort16* __restrict__ Bt_hi,
                          const ushort16* __restrict__ Bt_lo,
                          ushort16* __restrict__ C, int M) {
    constexpr int BM = 128, BK = 64;
    constexpr int NF = BN / 32;              // n-frags per wave (wave n-span = BN/2)
    __shared__ __align__(16) unsigned short Ah[BM * BK];
    __shared__ __align__(16) unsigned short Al[BM * BK];

    int tid = threadIdx.x;
    int wid = tid >> 6, lane = tid & 63;
    int wr = wid >> 1, wc = wid & 1;         // wave row/col in 2x2
    int rowBase = blockIdx.x * BM;
    int r = lane & 15, kg = lane >> 4;       // frag row(col) index, k-group
    int swzmask = (lane & 7) << 4;           // == (r&7)<<4

    f32x4 zero = {0.f, 0.f, 0.f, 0.f};
    f32x4 acc[4][NF];
#pragma unroll
    for (int m = 0; m < 4; m++)
#pragma unroll
        for (int n = 0; n < NF; n++) acc[m][n] = zero;

    int sk4 = (tid & 15) * 4;
    int sm0 = tid >> 4;

    for (int k0 = 0; k0 < K; k0 += BK) {
#pragma unroll
        for (int i = 0; i < 8; i++) {
            int m = sm0 + i * 16;
            int row = rowBase + m;
            float4 f = make_float4(0.f, 0.f, 0.f, 0.f);
            if (row < M) f = *(const float4*)(A + (size_t)row * K + k0 + sk4);
            ushort4 h, l;
            splitbf(f.x, h.x, l.x);
            splitbf(f.y, h.y, l.y);
            splitbf(f.z, h.z, l.z);
            splitbf(f.w, h.w, l.w);
            int bo = (m * BK + sk4) * 2;
            int swz = bo ^ ((m & 7) << 4);
            *(ushort4*)((char*)Ah + swz) = h;
            *(ushort4*)((char*)Al + swz) = l;
        }
        __syncthreads();

#pragma unroll
        for (int kk = 0; kk < BK / 32; kk++) {
            short8 ah[4], al[4];
            int abase = (wr * 64 + r) * (BK * 2) + kk * 64 + kg * 16;
#pragma unroll
            for (int m = 0; m < 4; m++) {
                int swz = (abase + m * (16 * BK * 2)) ^ swzmask;
                ah[m] = *(const short8*)((const char*)Ah + swz);
                al[m] = *(const short8*)((const char*)Al + swz);
            }
            short8 bh[NF], bl[NF];
#pragma unroll
            for (int n = 0; n < NF; n++) {
                size_t off = (size_t)(wc * (BN / 2) + n * 16 + r) * K + k0 + kk * 32 + kg * 8;
                bh[n] = *(const short8*)(Bt_hi + off);
                bl[n] = *(const short8*)(Bt_lo + off);
            }
#pragma unroll
            for (int m = 0; m < 4; m++)
#pragma unroll
                for (int n = 0; n < NF; n++) {
                    acc[m][n] = __builtin_amdgcn_mfma_f32_16x16x32_bf16(ah[m], bh[n], acc[m][n], 0, 0, 0);
                    acc[m][n] = __builtin_amdgcn_mfma_f32_16x16x32_bf16(ah[m], bl[n], acc[m][n], 0, 0, 0);
                    acc[m][n] = __builtin_amdgcn_mfma_f32_16x16x32_bf16(al[m], bh[n], acc[m][n], 0, 0, 0);
                }
        }
        __syncthreads();
    }

#pragma unroll
    for (int m = 0; m < 4; m++) {
        int row0 = rowBase + wr * 64 + m * 16 + kg * 4;
#pragma unroll
        for (int j = 0; j < 4; j++) {
            int row = row0 + j;
            if (row < M) {
#pragma unroll
                for (int n = 0; n < NF; n++) {
                    int col = wc * (BN / 2) + n * 16 + r;
                    C[(size_t)row * BN + col] = f2bf(acc[m][n][j]);
                }
            }
        }
    }
}

// ---------------- SpMM: wave per dst row, multi-edge-per-gather ----------------
// Lane map: slot = lane % LPR covers the row's 16B chunks (LPR*16B = D*2B = full row),
//           sub  = lane / LPR selects which edge this lane serves (EPG edges per gather).
// One global_load_dwordx4 fetches EPG edge-rows (1 KB); pair loads fetch EPG pairs.
// Each lane accumulates 8 dims; shfl_xor folds the EPG subgroups at row end.

template <int D, bool RELU>
__launch_bounds__(256)
__global__ void spmm_kernel(const ushort16* __restrict__ feat, const int2* __restrict__ csr_pair,
                            const int* __restrict__ row_ptr, float* __restrict__ out, int n) {
    constexpr int LPR = D * 2 / 16;      // lanes per row: 16 (D=128) or 8 (D=64)
    constexpr int EPG = 64 / LPR;        // edges per gather: 4 or 8
    int wid = threadIdx.x >> 6;
    int lane = threadIdx.x & 63;
    int row = blockIdx.x * 4 + wid;
    if (row >= n) return;
    int s = row_ptr[row], e = row_ptr[row + 1];

    int sub = lane / LPR;
    int slot = lane % LPR;
    const char* fbase = (const char*)feat + slot * 16;

    float acc[8];
#pragma unroll
    for (int j = 0; j < 8; j++) acc[j] = 0.f;

    for (int i = s; i < e; i += 2 * EPG) {
        int i0 = i + sub;
        int i1 = i + EPG + sub;
        int2 p0 = csr_pair[min(i0, e - 1)];
        int2 p1 = csr_pair[min(i1, e - 1)];
        float v0 = (i0 < e) ? __int_as_float(p0.y) : 0.f;
        float v1 = (i1 < e) ? __int_as_float(p1.y) : 0.f;
        uint4 u0 = *(const uint4*)(fbase + (size_t)p0.x * (D * 2));
        uint4 u1 = *(const uint4*)(fbase + (size_t)p1.x * (D * 2));
#pragma unroll
        for (int t = 0; t < 4; t++) {
            uint32 w0 = (&u0.x)[t];
            acc[2 * t]     += v0 * __uint_as_float(w0 << 16);
            acc[2 * t + 1] += v0 * __uint_as_float(w0 & 0xffff0000u);
        }
#pragma unroll
        for (int t = 0; t < 4; t++) {
            uint32 w1 = (&u1.x)[t];
            acc[2 * t]     += v1 * __uint_as_float(w1 << 16);
            acc[2 * t + 1] += v1 * __uint_as_float(w1 & 0xffff0000u);
        }
    }

    // fold the EPG edge-subgroups: lanes with equal slot sum across sub
#pragma unroll
    for (int m = LPR; m < 64; m <<= 1) {
#pragma unroll
        for (int j = 0; j < 8; j++) acc[j] += __shfl_xor(acc[j], m);
    }

    if (RELU) {
#pragma unroll
        for (int j = 0; j < 8; j++) acc[j] = acc[j] > 0.f ? acc[j] : 0.f;
    }

    if (lane < LPR) {
        float4* o = (float4*)(out + (size_t)row * D + slot * 8);
        o[0] = make_float4(acc[0], acc[1], acc[2], acc[3]);
        o[1] = make_float4(acc[4], acc[5], acc[6], acc[7]);
    }
}

// ---------------- launch ----------------

extern "C" void kernel_launch(void* const* d_in, const int* in_sizes, int n_in,
                              void* d_out, int out_size, void* d_ws, size_t ws_size,
                              hipStream_t stream) {
    const float* x    = (const float*)d_in[0];
    const float* adj  = (const float*)d_in[1];
    const float* w1   = (const float*)d_in[2];
    const float* w2   = (const float*)d_in[3];
    const int*   esrc = (const int*)d_in[4];
    const int*   edst = (const int*)d_in[5];
    float* out = (float*)d_out;

    const int N = N_NODES;
    const int E = N_EDGES;

    char* ws = (char*)d_ws;
    size_t off = 0;
    auto take = [&](size_t bytes) -> char* {
        char* p = ws + off;
        off = (off + bytes + 255) & ~(size_t)255;
        return p;
    };
    int*      bcnt    = (int*)take((size_t)NBUCK * 4);
    int*      bptr    = (int*)take((size_t)(NBUCK + 1) * 4);
    int*      cursor  = (int*)take((size_t)NBUCK * 4);
    int*      row_ptr = (int*)take((size_t)(N + 1) * 4);
    int2*     part    = (int2*)take((size_t)E * 8);          // becomes row-sorted CSR
    ushort16* pre1    = (ushort16*)take((size_t)N * HIDDEN * 2);   // bf16
    ushort16* pre2    = (ushort16*)take((size_t)N * OUT_DIM * 2);  // bf16
    float*    h       = (float*)take((size_t)N * HIDDEN * 4);      // fp32
    ushort16* w1t_hi  = (ushort16*)take((size_t)HIDDEN * IN_DIM * 2);
    ushort16* w1t_lo  = (ushort16*)take((size_t)HIDDEN * IN_DIM * 2);
    ushort16* w2t_hi  = (ushort16*)take((size_t)OUT_DIM * HIDDEN * 2);
    ushort16* w2t_lo  = (ushort16*)take((size_t)OUT_DIM * HIDDEN * 2);

    // weight transpose + split (tiny)
    splitw_kernel<<<(IN_DIM * HIDDEN + HIDDEN * OUT_DIM + 255) / 256, 256, 0, stream>>>(
        w1, w2, w1t_hi, w1t_lo, w2t_hi, w2t_lo);

    // CSR build: bucket partition -> per-bucket counting sort
    hipMemsetAsync(bcnt, 0, (size_t)NBUCK * 4, stream);
    hist_bucket<<<1024, 256, 0, stream>>>(edst, bcnt, E);
    bucket_scan<<<1, 256, 0, stream>>>(bcnt, bptr, cursor, row_ptr, E);
    partition_kernel<<<(E + CHUNK - 1) / CHUNK, 256, 0, stream>>>(esrc, edst, adj, cursor, part, E);
    bucket_to_csr<<<NBUCK, 256, 0, stream>>>(bptr, part, row_ptr);

    // Layer 1: pre1 = bf16(X@W1) via MFMA ; h = relu(A @ pre1) in fp32
    gemm_mfma<IN_DIM, HIDDEN><<<(N + 127) / 128, 256, 0, stream>>>(x, w1t_hi, w1t_lo, pre1, N);
    spmm_kernel<HIDDEN, true><<<(N + 3) / 4, 256, 0, stream>>>(pre1, part, row_ptr, h, N);

    // Layer 2: pre2 = bf16(h@W2) via MFMA ; out = A @ pre2 in fp32
    gemm_mfma<HIDDEN, OUT_DIM><<<(N + 127) / 128, 256, 0, stream>>>(h, w2t_hi, w2t_lo, pre2, N);
    spmm_kernel<OUT_DIM, false><<<(N + 3) / 4, 256, 0, stream>>>(pre2, part, row_ptr, out, N);
}

// Round 3
// 569.747 us; speedup vs baseline: 1.3470x; 1.0170x over previous
//
#include <hip/hip_runtime.h>

#define N_NODES 100000
#define N_EDGES 3200000
#define IN_DIM 256
#define HIDDEN 128
#define OUT_DIM 64

#define NBUCK 782        // ceil(100000 / 128) buckets of 128 dst rows
#define CHUNK 5120       // edges per partition block
#define BCAP 6144        // max edges per bucket for LDS sort (mean 4096, sd 64)

typedef unsigned int uint32;
typedef unsigned short ushort16;

typedef short short8 __attribute__((ext_vector_type(8)));   // 8 bf16 (4 VGPRs)
typedef float f32x4 __attribute__((ext_vector_type(4)));    // MFMA acc

// round-to-nearest-even f32 -> bf16
__device__ __forceinline__ ushort16 f2bf(float f) {
    uint32 u = __float_as_uint(f);
    u += 0x7fffu + ((u >> 16) & 1u);
    return (ushort16)(u >> 16);
}

// split f32 into bf16 hi + bf16 lo, f ~= hi + lo (error ~2^-16 rel)
__device__ __forceinline__ void splitbf(float f, unsigned short& hi, unsigned short& lo) {
    uint32 u = __float_as_uint(f);
    uint32 r = u + 0x7fffu + ((u >> 16) & 1u);
    hi = (unsigned short)(r >> 16);
    float hf = __uint_as_float((r >> 16) << 16);
    float res = f - hf;                    // exact (Sterbenz: same binade)
    uint32 v = __float_as_uint(res);
    lo = (unsigned short)((v + 0x7fffu + ((v >> 16) & 1u)) >> 16);
}

// ---------------- bucket histogram ----------------

__global__ __launch_bounds__(256)
void hist_bucket(const int* __restrict__ edst, int* __restrict__ bcnt, int E) {
    __shared__ int h[NBUCK];
    for (int b = threadIdx.x; b < NBUCK; b += 256) h[b] = 0;
    __syncthreads();
    for (int i = blockIdx.x * 256 + threadIdx.x; i < E; i += gridDim.x * 256)
        atomicAdd(&h[edst[i] >> 7], 1);
    __syncthreads();
    for (int b = threadIdx.x; b < NBUCK; b += 256) {
        int c = h[b];
        if (c) atomicAdd(&bcnt[b], c);
    }
}

// ---------------- bucket exclusive scan (one block) ----------------

__global__ __launch_bounds__(256)
void bucket_scan(const int* __restrict__ bcnt, int* __restrict__ bptr,
                 int* __restrict__ cursor, int* __restrict__ row_ptr, int E) {
    __shared__ int st[256];
    int tid = threadIdx.x;
    int v4[4];
    int s0 = 0;
#pragma unroll
    for (int k = 0; k < 4; k++) {
        int b = tid * 4 + k;
        v4[k] = (b < NBUCK) ? bcnt[b] : 0;
        s0 += v4[k];
    }
    st[tid] = s0;
    __syncthreads();
    for (int off = 1; off < 256; off <<= 1) {
        int t = (tid >= off) ? st[tid - off] : 0;
        __syncthreads();
        st[tid] += t;
        __syncthreads();
    }
    int run = st[tid] - s0;
#pragma unroll
    for (int k = 0; k < 4; k++) {
        int b = tid * 4 + k;
        if (b < NBUCK) { bptr[b] = run; cursor[b] = run; }
        run += v4[k];
    }
    if (tid == 255) bptr[NBUCK] = run;
    if (tid == 0) row_ptr[N_NODES] = E;
}

// ---------------- partition: LDS counting-sort per chunk ----------------
// payload p.x = src | (dst&127)<<17 ; p.y = val bits

__global__ __launch_bounds__(256)
void partition_kernel(const int* __restrict__ esrc, const int* __restrict__ edst,
                      const float* __restrict__ evals, int* __restrict__ cursor,
                      int2* __restrict__ part, int E) {
    __shared__ int hist[NBUCK];
    __shared__ int basepos[NBUCK];
    __shared__ int st[256];
    __shared__ unsigned short sbb[CHUNK];
    __shared__ int2 sbp[CHUNK];
    int tid = threadIdx.x;
    long base = (long)blockIdx.x * CHUNK;
    int cnt = (int)min((long)CHUNK, (long)E - base);

    for (int b = tid; b < NBUCK; b += 256) hist[b] = 0;
    __syncthreads();
    for (int j = tid; j < cnt; j += 256)
        atomicAdd(&hist[edst[base + j] >> 7], 1);
    __syncthreads();

    int v4[4];
    int s0 = 0;
#pragma unroll
    for (int k = 0; k < 4; k++) {
        int b = tid * 4 + k;
        v4[k] = (b < NBUCK) ? hist[b] : 0;
        s0 += v4[k];
    }
    st[tid] = s0;
    __syncthreads();
    for (int off = 1; off < 256; off <<= 1) {
        int t = (tid >= off) ? st[tid - off] : 0;
        __syncthreads();
        st[tid] += t;
        __syncthreads();
    }
    int run = st[tid] - s0;
#pragma unroll
    for (int k = 0; k < 4; k++) {
        int b = tid * 4 + k;
        if (b < NBUCK) {
            int gbase = (v4[k] > 0) ? atomicAdd(&cursor[b], v4[k]) : 0;
            basepos[b] = gbase - run;
            hist[b] = run;
        }
        run += v4[k];
    }
    __syncthreads();

    for (int j = tid; j < cnt; j += 256) {
        int d = edst[base + j];
        int b = d >> 7;
        int pos = atomicAdd(&hist[b], 1);
        sbb[pos] = (unsigned short)b;
        sbp[pos] = make_int2(esrc[base + j] | ((d & 127) << 17),
                             __float_as_int(evals[base + j]));
    }
    __syncthreads();

    for (int j = tid; j < cnt; j += 256) {
        int b = sbb[j];
        part[basepos[b] + j] = sbp[j];
    }
}

// ---------------- per-bucket counting sort -> row-sorted CSR (in place) ----------------

__global__ __launch_bounds__(256)
void bucket_to_csr(const int* __restrict__ bptr, int2* __restrict__ part,
                   int* __restrict__ row_ptr) {
    __shared__ int2 se[BCAP];
    __shared__ int rcnt[128];
    __shared__ int rcur[128];
    int tid = threadIdx.x;
    int b = blockIdx.x;
    int s = bptr[b], e = bptr[b + 1];
    int cnt = min(e - s, BCAP);

    if (tid < 128) rcnt[tid] = 0;
    __syncthreads();
    for (int j = tid; j < cnt; j += 256) {
        int2 p = part[s + j];
        se[j] = p;
        atomicAdd(&rcnt[p.x >> 17], 1);
    }
    __syncthreads();

    int v = (tid < 128) ? rcnt[tid] : 0;
    if (tid < 128) rcur[tid] = v;
    __syncthreads();
    for (int off = 1; off < 128; off <<= 1) {
        int t = 0;
        if (tid < 128 && tid >= off) t = rcur[tid - off];
        __syncthreads();
        if (tid < 128 && tid >= off) rcur[tid] += t;
        __syncthreads();
    }
    if (tid < 128) {
        int excl = rcur[tid] - v;
        rcur[tid] = excl;
        int row = b * 128 + tid;
        if (row < N_NODES) row_ptr[row] = s + excl;
    }
    __syncthreads();

    for (int j = tid; j < cnt; j += 256) {
        int2 p = se[j];
        int r = p.x >> 17;
        int pos = atomicAdd(&rcur[r], 1);
        part[s + pos] = make_int2(p.x & 0x1FFFF, p.y);
    }
}

// ---------------- weight split to MFMA-fragment-major layout (tiny, once) ----------------
// Layout: [kblk][nfrag][lane][8]  with  n = nfrag*16 + (lane&15), k = kblk*32 + (lane>>4)*8 + j
// -> a wave's fragment load is base + lane*16B: one coalesced 1KB load per instruction.

__global__ __launch_bounds__(256)
void splitw_kernel(const float* __restrict__ w1, const float* __restrict__ w2,
                   unsigned short* __restrict__ w1f_hi, unsigned short* __restrict__ w1f_lo,
                   unsigned short* __restrict__ w2f_hi, unsigned short* __restrict__ w2f_lo) {
    const int W1_SLOTS = (IN_DIM / 32) * (HIDDEN / 16) * 64;   // 8*8*64 = 4096
    const int W2_SLOTS = (HIDDEN / 32) * (OUT_DIM / 16) * 64;  // 4*4*64 = 1024
    int g = blockIdx.x * 256 + threadIdx.x;
    if (g < W1_SLOTS) {
        int lane = g & 63;
        int rest = g >> 6;
        int nfrag = rest & 7;              // HIDDEN/16 = 8
        int kblk = rest >> 3;
        int n = nfrag * 16 + (lane & 15);
        int k0 = kblk * 32 + (lane >> 4) * 8;
#pragma unroll
        for (int j = 0; j < 8; j++) {
            unsigned short h, l;
            splitbf(w1[(size_t)(k0 + j) * HIDDEN + n], h, l);
            w1f_hi[(size_t)g * 8 + j] = h;
            w1f_lo[(size_t)g * 8 + j] = l;
        }
    } else if (g < W1_SLOTS + W2_SLOTS) {
        int g2 = g - W1_SLOTS;
        int lane = g2 & 63;
        int rest = g2 >> 6;
        int nfrag = rest & 3;              // OUT_DIM/16 = 4
        int kblk = rest >> 2;
        int n = nfrag * 16 + (lane & 15);
        int k0 = kblk * 32 + (lane >> 4) * 8;
#pragma unroll
        for (int j = 0; j < 8; j++) {
            unsigned short h, l;
            splitbf(w2[(size_t)(k0 + j) * OUT_DIM + n], h, l);
            w2f_hi[(size_t)g2 * 8 + j] = h;
            w2f_lo[(size_t)g2 * 8 + j] = l;
        }
    }
}

// ---------------- MFMA GEMM: C(bf16) = A(fp32) @ B, split-bf16 3-product ----------------
// B in fragment-major layout (see splitw_kernel): coalesced lane*16B loads.

template <int K, int BN>
__launch_bounds__(256)
__global__ void gemm_mfma(const float* __restrict__ A,
                          const unsigned short* __restrict__ Bf_hi,
                          const unsigned short* __restrict__ Bf_lo,
                          ushort16* __restrict__ C, int M) {
    constexpr int BM = 128, BK = 64;
    constexpr int NF = BN / 32;              // n-frags per wave (wave n-span = BN/2)
    __shared__ __align__(16) unsigned short Ah[BM * BK];
    __shared__ __align__(16) unsigned short Al[BM * BK];

    int tid = threadIdx.x;
    int wid = tid >> 6, lane = tid & 63;
    int wr = wid >> 1, wc = wid & 1;         // wave row/col in 2x2
    int rowBase = blockIdx.x * BM;
    int r = lane & 15, kg = lane >> 4;       // frag row(col) index, k-group
    int swzmask = (lane & 7) << 4;           // == (r&7)<<4

    f32x4 zero = {0.f, 0.f, 0.f, 0.f};
    f32x4 acc[4][NF];
#pragma unroll
    for (int m = 0; m < 4; m++)
#pragma unroll
        for (int n = 0; n < NF; n++) acc[m][n] = zero;

    int sk4 = (tid & 15) * 4;
    int sm0 = tid >> 4;

    for (int k0 = 0; k0 < K; k0 += BK) {
#pragma unroll
        for (int i = 0; i < 8; i++) {
            int m = sm0 + i * 16;
            int row = rowBase + m;
            float4 f = make_float4(0.f, 0.f, 0.f, 0.f);
            if (row < M) f = *(const float4*)(A + (size_t)row * K + k0 + sk4);
            ushort4 h, l;
            splitbf(f.x, h.x, l.x);
            splitbf(f.y, h.y, l.y);
            splitbf(f.z, h.z, l.z);
            splitbf(f.w, h.w, l.w);
            int bo = (m * BK + sk4) * 2;
            int swz = bo ^ ((m & 7) << 4);
            *(ushort4*)((char*)Ah + swz) = h;
            *(ushort4*)((char*)Al + swz) = l;
        }
        __syncthreads();

#pragma unroll
        for (int kk = 0; kk < BK / 32; kk++) {
            short8 ah[4], al[4];
            int abase = (wr * 64 + r) * (BK * 2) + kk * 64 + kg * 16;
#pragma unroll
            for (int m = 0; m < 4; m++) {
                int swz = (abase + m * (16 * BK * 2)) ^ swzmask;
                ah[m] = *(const short8*)((const char*)Ah + swz);
                al[m] = *(const short8*)((const char*)Al + swz);
            }
            short8 bh[NF], bl[NF];
            int kblk = (k0 >> 5) + kk;
#pragma unroll
            for (int n = 0; n < NF; n++) {
                int nf = wc * NF + n;
                size_t off = ((size_t)(kblk * (BN / 16) + nf) * 64 + lane) * 8;
                bh[n] = *(const short8*)(Bf_hi + off);
                bl[n] = *(const short8*)(Bf_lo + off);
            }
#pragma unroll
            for (int m = 0; m < 4; m++)
#pragma unroll
                for (int n = 0; n < NF; n++) {
                    acc[m][n] = __builtin_amdgcn_mfma_f32_16x16x32_bf16(ah[m], bh[n], acc[m][n], 0, 0, 0);
                    acc[m][n] = __builtin_amdgcn_mfma_f32_16x16x32_bf16(ah[m], bl[n], acc[m][n], 0, 0, 0);
                    acc[m][n] = __builtin_amdgcn_mfma_f32_16x16x32_bf16(al[m], bh[n], acc[m][n], 0, 0, 0);
                }
        }
        __syncthreads();
    }

#pragma unroll
    for (int m = 0; m < 4; m++) {
        int row0 = rowBase + wr * 64 + m * 16 + kg * 4;
#pragma unroll
        for (int j = 0; j < 4; j++) {
            int row = row0 + j;
            if (row < M) {
#pragma unroll
                for (int n = 0; n < NF; n++) {
                    int col = wc * (BN / 2) + n * 16 + r;
                    C[(size_t)row * BN + col] = f2bf(acc[m][n][j]);
                }
            }
        }
    }
}

// ---------------- fused SpMM(layer1) + GEMM(layer2): one block per 128-row bucket ----------------
// Phase 1: 8 waves, wave w gathers rows w*16..w*16+15 (4 edge-rows per uint4 gather, 4 in flight),
//          relu + split-bf16, store swizzled into LDS (Hh/Hl, 32KB each).
// Phase 2: wave w computes pre2[w*16..w*16+15][0..63] = H @ W2 via 16x16x32 MFMA (3-product),
//          A-frags from LDS, B-frags coalesced from fragment-major w2f.

__launch_bounds__(512)
__global__ void spmm_gemm_fused(const ushort16* __restrict__ feat, const int2* __restrict__ csr_pair,
                                const int* __restrict__ row_ptr,
                                const unsigned short* __restrict__ w2f_hi,
                                const unsigned short* __restrict__ w2f_lo,
                                ushort16* __restrict__ pre2, int n) {
    __shared__ __align__(16) unsigned short Hh[128 * 128];   // 32 KB
    __shared__ __align__(16) unsigned short Hl[128 * 128];   // 32 KB
    int tid = threadIdx.x;
    int wid = tid >> 6;              // 0..7
    int lane = tid & 63;
    int sub = lane >> 4;             // 0..3 : which edge of the gather-quad
    int slot = lane & 15;            // 0..15: 16B chunk of the 256B feature row
    int bucket = blockIdx.x;
    const char* fbase = (const char*)feat + slot * 16;

    // ---- phase 1: gather + reduce 16 rows ----
    for (int rl = 0; rl < 16; rl++) {
        int lrow = wid * 16 + rl;
        int row = bucket * 128 + lrow;
        int s = 0, e = 0;
        if (row < n) { s = row_ptr[row]; e = row_ptr[row + 1]; }
        float acc0[8];
#pragma unroll
        for (int j = 0; j < 8; j++) acc0[j] = 0.f;

        for (int i = s; i < e; i += 16) {
            int2 pp[4]; float vv[4]; uint4 uu[4];
#pragma unroll
            for (int q = 0; q < 4; q++) {
                int ii = i + q * 4 + sub;
                pp[q] = csr_pair[min(ii, e - 1)];
                vv[q] = (ii < e) ? __int_as_float(pp[q].y) : 0.f;
            }
#pragma unroll
            for (int q = 0; q < 4; q++)
                uu[q] = *(const uint4*)(fbase + (size_t)pp[q].x * 256);
#pragma unroll
            for (int q = 0; q < 4; q++) {
#pragma unroll
                for (int t = 0; t < 4; t++) {
                    uint32 w = (&uu[q].x)[t];
                    acc0[2 * t]     += vv[q] * __uint_as_float(w << 16);
                    acc0[2 * t + 1] += vv[q] * __uint_as_float(w & 0xffff0000u);
                }
            }
        }

        // fold the 4 edge-subgroups (lanes with equal slot)
#pragma unroll
        for (int m = 16; m < 64; m <<= 1) {
#pragma unroll
            for (int j = 0; j < 8; j++) acc0[j] += __shfl_xor(acc0[j], m);
        }

        if (lane < 16) {
            short8 hv, lv;
#pragma unroll
            for (int j = 0; j < 8; j++) {
                float a = acc0[j] > 0.f ? acc0[j] : 0.f;   // relu
                unsigned short hh, ll;
                splitbf(a, hh, ll);
                hv[j] = (short)hh;
                lv[j] = (short)ll;
            }
            int bo = lrow * 256 + slot * 16;
            int swz = bo ^ ((lrow & 7) << 4);
            *(short8*)((char*)Hh + swz) = hv;
            *(short8*)((char*)Hl + swz) = lv;
        }
    }
    __syncthreads();

    // ---- phase 2: pre2 strip = H[w*16..+15][:] @ W2 ----
    int r = lane & 15, kg = lane >> 4;
    int lrow2 = wid * 16 + r;
    f32x4 zero = {0.f, 0.f, 0.f, 0.f};
    f32x4 acc2[4];
#pragma unroll
    for (int nn = 0; nn < 4; nn++) acc2[nn] = zero;

#pragma unroll
    for (int kk = 0; kk < 4; kk++) {
        int bo = lrow2 * 256 + kk * 64 + kg * 16;
        int swz = bo ^ ((lrow2 & 7) << 4);
        short8 ah = *(const short8*)((const char*)Hh + swz);
        short8 al = *(const short8*)((const char*)Hl + swz);
#pragma unroll
        for (int nn = 0; nn < 4; nn++) {
            size_t off = ((size_t)(kk * 4 + nn) * 64 + lane) * 8;
            short8 bh = *(const short8*)(w2f_hi + off);
            short8 bl = *(const short8*)(w2f_lo + off);
            acc2[nn] = __builtin_amdgcn_mfma_f32_16x16x32_bf16(ah, bh, acc2[nn], 0, 0, 0);
            acc2[nn] = __builtin_amdgcn_mfma_f32_16x16x32_bf16(ah, bl, acc2[nn], 0, 0, 0);
            acc2[nn] = __builtin_amdgcn_mfma_f32_16x16x32_bf16(al, bh, acc2[nn], 0, 0, 0);
        }
    }

#pragma unroll
    for (int j = 0; j < 4; j++) {
        int row = bucket * 128 + wid * 16 + kg * 4 + j;
        if (row < n) {
#pragma unroll
            for (int nn = 0; nn < 4; nn++)
                pre2[(size_t)row * OUT_DIM + nn * 16 + r] = f2bf(acc2[nn][j]);
        }
    }
}

// ---------------- SpMM: wave per dst row, multi-edge-per-gather ----------------

template <int D, bool RELU>
__launch_bounds__(256)
__global__ void spmm_kernel(const ushort16* __restrict__ feat, const int2* __restrict__ csr_pair,
                            const int* __restrict__ row_ptr, float* __restrict__ out, int n) {
    constexpr int LPR = D * 2 / 16;      // lanes per row
    constexpr int EPG = 64 / LPR;        // edges per gather
    int wid = threadIdx.x >> 6;
    int lane = threadIdx.x & 63;
    int row = blockIdx.x * 4 + wid;
    if (row >= n) return;
    int s = row_ptr[row], e = row_ptr[row + 1];

    int sub = lane / LPR;
    int slot = lane % LPR;
    const char* fbase = (const char*)feat + slot * 16;

    float acc[8];
#pragma unroll
    for (int j = 0; j < 8; j++) acc[j] = 0.f;

    for (int i = s; i < e; i += 2 * EPG) {
        int i0 = i + sub;
        int i1 = i + EPG + sub;
        int2 p0 = csr_pair[min(i0, e - 1)];
        int2 p1 = csr_pair[min(i1, e - 1)];
        float v0 = (i0 < e) ? __int_as_float(p0.y) : 0.f;
        float v1 = (i1 < e) ? __int_as_float(p1.y) : 0.f;
        uint4 u0 = *(const uint4*)(fbase + (size_t)p0.x * (D * 2));
        uint4 u1 = *(const uint4*)(fbase + (size_t)p1.x * (D * 2));
#pragma unroll
        for (int t = 0; t < 4; t++) {
            uint32 w0 = (&u0.x)[t];
            acc[2 * t]     += v0 * __uint_as_float(w0 << 16);
            acc[2 * t + 1] += v0 * __uint_as_float(w0 & 0xffff0000u);
        }
#pragma unroll
        for (int t = 0; t < 4; t++) {
            uint32 w1 = (&u1.x)[t];
            acc[2 * t]     += v1 * __uint_as_float(w1 << 16);
            acc[2 * t + 1] += v1 * __uint_as_float(w1 & 0xffff0000u);
        }
    }

#pragma unroll
    for (int m = LPR; m < 64; m <<= 1) {
#pragma unroll
        for (int j = 0; j < 8; j++) acc[j] += __shfl_xor(acc[j], m);
    }

    if (RELU) {
#pragma unroll
        for (int j = 0; j < 8; j++) acc[j] = acc[j] > 0.f ? acc[j] : 0.f;
    }

    if (lane < LPR) {
        float4* o = (float4*)(out + (size_t)row * D + slot * 8);
        o[0] = make_float4(acc[0], acc[1], acc[2], acc[3]);
        o[1] = make_float4(acc[4], acc[5], acc[6], acc[7]);
    }
}

// ---------------- launch ----------------

extern "C" void kernel_launch(void* const* d_in, const int* in_sizes, int n_in,
                              void* d_out, int out_size, void* d_ws, size_t ws_size,
                              hipStream_t stream) {
    const float* x    = (const float*)d_in[0];
    const float* adj  = (const float*)d_in[1];
    const float* w1   = (const float*)d_in[2];
    const float* w2   = (const float*)d_in[3];
    const int*   esrc = (const int*)d_in[4];
    const int*   edst = (const int*)d_in[5];
    float* out = (float*)d_out;

    const int N = N_NODES;
    const int E = N_EDGES;

    char* ws = (char*)d_ws;
    size_t off = 0;
    auto take = [&](size_t bytes) -> char* {
        char* p = ws + off;
        off = (off + bytes + 255) & ~(size_t)255;
        return p;
    };
    int*      bcnt    = (int*)take((size_t)NBUCK * 4);
    int*      bptr    = (int*)take((size_t)(NBUCK + 1) * 4);
    int*      cursor  = (int*)take((size_t)NBUCK * 4);
    int*      row_ptr = (int*)take((size_t)(N + 1) * 4);
    int2*     part    = (int2*)take((size_t)E * 8);          // becomes row-sorted CSR
    ushort16* pre1    = (ushort16*)take((size_t)N * HIDDEN * 2);   // bf16
    ushort16* pre2    = (ushort16*)take((size_t)N * OUT_DIM * 2);  // bf16
    unsigned short* w1f_hi = (unsigned short*)take((size_t)HIDDEN * IN_DIM * 2);
    unsigned short* w1f_lo = (unsigned short*)take((size_t)HIDDEN * IN_DIM * 2);
    unsigned short* w2f_hi = (unsigned short*)take((size_t)OUT_DIM * HIDDEN * 2);
    unsigned short* w2f_lo = (unsigned short*)take((size_t)OUT_DIM * HIDDEN * 2);

    // weight split to fragment-major (tiny)
    splitw_kernel<<<20, 256, 0, stream>>>(w1, w2, w1f_hi, w1f_lo, w2f_hi, w2f_lo);

    // CSR build: bucket partition -> per-bucket counting sort
    hipMemsetAsync(bcnt, 0, (size_t)NBUCK * 4, stream);
    hist_bucket<<<1024, 256, 0, stream>>>(edst, bcnt, E);
    bucket_scan<<<1, 256, 0, stream>>>(bcnt, bptr, cursor, row_ptr, E);
    partition_kernel<<<(E + CHUNK - 1) / CHUNK, 256, 0, stream>>>(esrc, edst, adj, cursor, part, E);
    bucket_to_csr<<<NBUCK, 256, 0, stream>>>(bptr, part, row_ptr);

    // Layer 1 GEMM: pre1 = bf16(X@W1) via MFMA
    gemm_mfma<IN_DIM, HIDDEN><<<(N + 127) / 128, 256, 0, stream>>>(x, w1f_hi, w1f_lo, pre1, N);

    // Fused: h = relu(A@pre1) (LDS-resident) ; pre2 = bf16(h@W2)
    spmm_gemm_fused<<<NBUCK, 512, 0, stream>>>(pre1, part, row_ptr, w2f_hi, w2f_lo, pre2, N);

    // Layer 2 SpMM: out = A @ pre2 in fp32
    spmm_kernel<OUT_DIM, false><<<(N + 3) / 4, 256, 0, stream>>>(pre2, part, row_ptr, out, N);
}

// Round 4
// 548.973 us; speedup vs baseline: 1.3979x; 1.0378x over previous
//
#include <hip/hip_runtime.h>

#define N_NODES 100000
#define N_EDGES 3200000
#define IN_DIM 256
#define HIDDEN 128
#define OUT_DIM 64

#define NBUCK 782        // ceil(100000 / 128) buckets of 128 dst rows
#define CHUNK 5120       // edges per partition block
#define BCAP 6144        // max edges per bucket for LDS sort (mean 4096, sd 64)

typedef unsigned int uint32;
typedef unsigned short ushort16;

typedef short short8 __attribute__((ext_vector_type(8)));   // 8 bf16 (4 VGPRs)
typedef float f32x4 __attribute__((ext_vector_type(4)));    // MFMA acc

// round-to-nearest-even f32 -> bf16
__device__ __forceinline__ ushort16 f2bf(float f) {
    uint32 u = __float_as_uint(f);
    u += 0x7fffu + ((u >> 16) & 1u);
    return (ushort16)(u >> 16);
}

// split f32 into bf16 hi + bf16 lo, f ~= hi + lo (error ~2^-16 rel)
__device__ __forceinline__ void splitbf(float f, unsigned short& hi, unsigned short& lo) {
    uint32 u = __float_as_uint(f);
    uint32 r = u + 0x7fffu + ((u >> 16) & 1u);
    hi = (unsigned short)(r >> 16);
    float hf = __uint_as_float((r >> 16) << 16);
    float res = f - hf;                    // exact (Sterbenz: same binade)
    uint32 v = __float_as_uint(res);
    lo = (unsigned short)((v + 0x7fffu + ((v >> 16) & 1u)) >> 16);
}

// ---------------- bucket histogram ----------------

__global__ __launch_bounds__(256)
void hist_bucket(const int* __restrict__ edst, int* __restrict__ bcnt, int E) {
    __shared__ int h[NBUCK];
    for (int b = threadIdx.x; b < NBUCK; b += 256) h[b] = 0;
    __syncthreads();
    for (int i = blockIdx.x * 256 + threadIdx.x; i < E; i += gridDim.x * 256)
        atomicAdd(&h[edst[i] >> 7], 1);
    __syncthreads();
    for (int b = threadIdx.x; b < NBUCK; b += 256) {
        int c = h[b];
        if (c) atomicAdd(&bcnt[b], c);
    }
}

// ---------------- bucket exclusive scan (one block) ----------------

__global__ __launch_bounds__(256)
void bucket_scan(const int* __restrict__ bcnt, int* __restrict__ bptr,
                 int* __restrict__ cursor, int* __restrict__ row_ptr, int E) {
    __shared__ int st[256];
    int tid = threadIdx.x;
    int v4[4];
    int s0 = 0;
#pragma unroll
    for (int k = 0; k < 4; k++) {
        int b = tid * 4 + k;
        v4[k] = (b < NBUCK) ? bcnt[b] : 0;
        s0 += v4[k];
    }
    st[tid] = s0;
    __syncthreads();
    for (int off = 1; off < 256; off <<= 1) {
        int t = (tid >= off) ? st[tid - off] : 0;
        __syncthreads();
        st[tid] += t;
        __syncthreads();
    }
    int run = st[tid] - s0;
#pragma unroll
    for (int k = 0; k < 4; k++) {
        int b = tid * 4 + k;
        if (b < NBUCK) { bptr[b] = run; cursor[b] = run; }
        run += v4[k];
    }
    if (tid == 255) bptr[NBUCK] = run;
    if (tid == 0) row_ptr[N_NODES] = E;
}

// ---------------- partition: LDS counting-sort per chunk ----------------
// payload p.x = src | (dst&127)<<17 ; p.y = val bits

__global__ __launch_bounds__(256)
void partition_kernel(const int* __restrict__ esrc, const int* __restrict__ edst,
                      const float* __restrict__ evals, int* __restrict__ cursor,
                      int2* __restrict__ part, int E) {
    __shared__ int hist[NBUCK];
    __shared__ int basepos[NBUCK];
    __shared__ int st[256];
    __shared__ unsigned short sbb[CHUNK];
    __shared__ int2 sbp[CHUNK];
    int tid = threadIdx.x;
    long base = (long)blockIdx.x * CHUNK;
    int cnt = (int)min((long)CHUNK, (long)E - base);

    for (int b = tid; b < NBUCK; b += 256) hist[b] = 0;
    __syncthreads();
    for (int j = tid; j < cnt; j += 256)
        atomicAdd(&hist[edst[base + j] >> 7], 1);
    __syncthreads();

    int v4[4];
    int s0 = 0;
#pragma unroll
    for (int k = 0; k < 4; k++) {
        int b = tid * 4 + k;
        v4[k] = (b < NBUCK) ? hist[b] : 0;
        s0 += v4[k];
    }
    st[tid] = s0;
    __syncthreads();
    for (int off = 1; off < 256; off <<= 1) {
        int t = (tid >= off) ? st[tid - off] : 0;
        __syncthreads();
        st[tid] += t;
        __syncthreads();
    }
    int run = st[tid] - s0;
#pragma unroll
    for (int k = 0; k < 4; k++) {
        int b = tid * 4 + k;
        if (b < NBUCK) {
            int gbase = (v4[k] > 0) ? atomicAdd(&cursor[b], v4[k]) : 0;
            basepos[b] = gbase - run;
            hist[b] = run;
        }
        run += v4[k];
    }
    __syncthreads();

    for (int j = tid; j < cnt; j += 256) {
        int d = edst[base + j];
        int b = d >> 7;
        int pos = atomicAdd(&hist[b], 1);
        sbb[pos] = (unsigned short)b;
        sbp[pos] = make_int2(esrc[base + j] | ((d & 127) << 17),
                             __float_as_int(evals[base + j]));
    }
    __syncthreads();

    for (int j = tid; j < cnt; j += 256) {
        int b = sbb[j];
        part[basepos[b] + j] = sbp[j];
    }
}

// ---------------- per-bucket counting sort -> row-sorted CSR (in place) ----------------

__global__ __launch_bounds__(256)
void bucket_to_csr(const int* __restrict__ bptr, int2* __restrict__ part,
                   int* __restrict__ row_ptr) {
    __shared__ int2 se[BCAP];
    __shared__ int rcnt[128];
    __shared__ int rcur[128];
    int tid = threadIdx.x;
    int b = blockIdx.x;
    int s = bptr[b], e = bptr[b + 1];
    int cnt = min(e - s, BCAP);

    if (tid < 128) rcnt[tid] = 0;
    __syncthreads();
    for (int j = tid; j < cnt; j += 256) {
        int2 p = part[s + j];
        se[j] = p;
        atomicAdd(&rcnt[p.x >> 17], 1);
    }
    __syncthreads();

    int v = (tid < 128) ? rcnt[tid] : 0;
    if (tid < 128) rcur[tid] = v;
    __syncthreads();
    for (int off = 1; off < 128; off <<= 1) {
        int t = 0;
        if (tid < 128 && tid >= off) t = rcur[tid - off];
        __syncthreads();
        if (tid < 128 && tid >= off) rcur[tid] += t;
        __syncthreads();
    }
    if (tid < 128) {
        int excl = rcur[tid] - v;
        rcur[tid] = excl;
        int row = b * 128 + tid;
        if (row < N_NODES) row_ptr[row] = s + excl;
    }
    __syncthreads();

    for (int j = tid; j < cnt; j += 256) {
        int2 p = se[j];
        int r = p.x >> 17;
        int pos = atomicAdd(&rcur[r], 1);
        part[s + pos] = make_int2(p.x & 0x1FFFF, p.y);
    }
}

// ---------------- weight split to MFMA-fragment-major layout (tiny, once) ----------------
// Layout: [kblk][nfrag][lane][8]  with  n = nfrag*16 + (lane&15), k = kblk*32 + (lane>>4)*8 + j
// -> a wave's fragment load is base + lane*16B: one coalesced 1KB load per instruction.

__global__ __launch_bounds__(256)
void splitw_kernel(const float* __restrict__ w1, const float* __restrict__ w2,
                   unsigned short* __restrict__ w1f_hi, unsigned short* __restrict__ w1f_lo,
                   unsigned short* __restrict__ w2f_hi, unsigned short* __restrict__ w2f_lo) {
    const int W1_SLOTS = (IN_DIM / 32) * (HIDDEN / 16) * 64;   // 8*8*64 = 4096
    const int W2_SLOTS = (HIDDEN / 32) * (OUT_DIM / 16) * 64;  // 4*4*64 = 1024
    int g = blockIdx.x * 256 + threadIdx.x;
    if (g < W1_SLOTS) {
        int lane = g & 63;
        int rest = g >> 6;
        int nfrag = rest & 7;              // HIDDEN/16 = 8
        int kblk = rest >> 3;
        int n = nfrag * 16 + (lane & 15);
        int k0 = kblk * 32 + (lane >> 4) * 8;
#pragma unroll
        for (int j = 0; j < 8; j++) {
            unsigned short h, l;
            splitbf(w1[(size_t)(k0 + j) * HIDDEN + n], h, l);
            w1f_hi[(size_t)g * 8 + j] = h;
            w1f_lo[(size_t)g * 8 + j] = l;
        }
    } else if (g < W1_SLOTS + W2_SLOTS) {
        int g2 = g - W1_SLOTS;
        int lane = g2 & 63;
        int rest = g2 >> 6;
        int nfrag = rest & 3;              // OUT_DIM/16 = 4
        int kblk = rest >> 2;
        int n = nfrag * 16 + (lane & 15);
        int k0 = kblk * 32 + (lane >> 4) * 8;
#pragma unroll
        for (int j = 0; j < 8; j++) {
            unsigned short h, l;
            splitbf(w2[(size_t)(k0 + j) * OUT_DIM + n], h, l);
            w2f_hi[(size_t)g2 * 8 + j] = h;
            w2f_lo[(size_t)g2 * 8 + j] = l;
        }
    }
}

// ---------------- MFMA GEMM: C(bf16) = A(fp32) @ B, split-bf16 3-product ----------------
// B in fragment-major layout (see splitw_kernel): coalesced lane*16B loads.

template <int K, int BN>
__launch_bounds__(256)
__global__ void gemm_mfma(const float* __restrict__ A,
                          const unsigned short* __restrict__ Bf_hi,
                          const unsigned short* __restrict__ Bf_lo,
                          ushort16* __restrict__ C, int M) {
    constexpr int BM = 128, BK = 64;
    constexpr int NF = BN / 32;              // n-frags per wave (wave n-span = BN/2)
    __shared__ __align__(16) unsigned short Ah[BM * BK];
    __shared__ __align__(16) unsigned short Al[BM * BK];

    int tid = threadIdx.x;
    int wid = tid >> 6, lane = tid & 63;
    int wr = wid >> 1, wc = wid & 1;         // wave row/col in 2x2
    int rowBase = blockIdx.x * BM;
    int r = lane & 15, kg = lane >> 4;       // frag row(col) index, k-group
    int swzmask = (lane & 7) << 4;           // == (r&7)<<4

    f32x4 zero = {0.f, 0.f, 0.f, 0.f};
    f32x4 acc[4][NF];
#pragma unroll
    for (int m = 0; m < 4; m++)
#pragma unroll
        for (int n = 0; n < NF; n++) acc[m][n] = zero;

    int sk4 = (tid & 15) * 4;
    int sm0 = tid >> 4;

    for (int k0 = 0; k0 < K; k0 += BK) {
#pragma unroll
        for (int i = 0; i < 8; i++) {
            int m = sm0 + i * 16;
            int row = rowBase + m;
            float4 f = make_float4(0.f, 0.f, 0.f, 0.f);
            if (row < M) f = *(const float4*)(A + (size_t)row * K + k0 + sk4);
            ushort4 h, l;
            splitbf(f.x, h.x, l.x);
            splitbf(f.y, h.y, l.y);
            splitbf(f.z, h.z, l.z);
            splitbf(f.w, h.w, l.w);
            int bo = (m * BK + sk4) * 2;
            int swz = bo ^ ((m & 7) << 4);
            *(ushort4*)((char*)Ah + swz) = h;
            *(ushort4*)((char*)Al + swz) = l;
        }
        __syncthreads();

#pragma unroll
        for (int kk = 0; kk < BK / 32; kk++) {
            short8 ah[4], al[4];
            int abase = (wr * 64 + r) * (BK * 2) + kk * 64 + kg * 16;
#pragma unroll
            for (int m = 0; m < 4; m++) {
                int swz = (abase + m * (16 * BK * 2)) ^ swzmask;
                ah[m] = *(const short8*)((const char*)Ah + swz);
                al[m] = *(const short8*)((const char*)Al + swz);
            }
            short8 bh[NF], bl[NF];
            int kblk = (k0 >> 5) + kk;
#pragma unroll
            for (int n = 0; n < NF; n++) {
                int nf = wc * NF + n;
                size_t off = ((size_t)(kblk * (BN / 16) + nf) * 64 + lane) * 8;
                bh[n] = *(const short8*)(Bf_hi + off);
                bl[n] = *(const short8*)(Bf_lo + off);
            }
#pragma unroll
            for (int m = 0; m < 4; m++)
#pragma unroll
                for (int n = 0; n < NF; n++) {
                    acc[m][n] = __builtin_amdgcn_mfma_f32_16x16x32_bf16(ah[m], bh[n], acc[m][n], 0, 0, 0);
                    acc[m][n] = __builtin_amdgcn_mfma_f32_16x16x32_bf16(ah[m], bl[n], acc[m][n], 0, 0, 0);
                    acc[m][n] = __builtin_amdgcn_mfma_f32_16x16x32_bf16(al[m], bh[n], acc[m][n], 0, 0, 0);
                }
        }
        __syncthreads();
    }

#pragma unroll
    for (int m = 0; m < 4; m++) {
        int row0 = rowBase + wr * 64 + m * 16 + kg * 4;
#pragma unroll
        for (int j = 0; j < 4; j++) {
            int row = row0 + j;
            if (row < M) {
#pragma unroll
                for (int n = 0; n < NF; n++) {
                    int col = wc * (BN / 2) + n * 16 + r;
                    C[(size_t)row * BN + col] = f2bf(acc[m][n][j]);
                }
            }
        }
    }
}

// ---------------- SpMM: wave per dst row, multi-edge-per-gather, 4-deep pipeline ----------------
// Lane map: slot = lane % LPR covers the row's 16B chunks (LPR*16B = D*2B = full row),
//           sub  = lane / LPR selects which edge this lane serves (EPG edges per gather).
// One global_load_dwordx4 fetches EPG edge-rows; 4 gathers kept in flight per wave.

template <int D, bool RELU>
__launch_bounds__(256)
__global__ void spmm_kernel(const ushort16* __restrict__ feat, const int2* __restrict__ csr_pair,
                            const int* __restrict__ row_ptr, float* __restrict__ out, int n) {
    constexpr int LPR = D * 2 / 16;      // lanes per row: 16 (D=128) or 8 (D=64)
    constexpr int EPG = 64 / LPR;        // edges per gather: 4 or 8
    int wid = threadIdx.x >> 6;
    int lane = threadIdx.x & 63;
    int row = blockIdx.x * 4 + wid;
    if (row >= n) return;
    int s = row_ptr[row], e = row_ptr[row + 1];

    int sub = lane / LPR;
    int slot = lane % LPR;
    const char* fbase = (const char*)feat + slot * 16;

    float acc[8];
#pragma unroll
    for (int j = 0; j < 8; j++) acc[j] = 0.f;

    for (int i = s; i < e; i += 4 * EPG) {
        int2 p[4]; float v[4]; uint4 u[4];
#pragma unroll
        for (int q = 0; q < 4; q++) {
            int ii = i + q * EPG + sub;
            p[q] = csr_pair[min(ii, e - 1)];
            v[q] = (ii < e) ? __int_as_float(p[q].y) : 0.f;
        }
#pragma unroll
        for (int q = 0; q < 4; q++)
            u[q] = *(const uint4*)(fbase + (size_t)p[q].x * (D * 2));
#pragma unroll
        for (int q = 0; q < 4; q++) {
#pragma unroll
            for (int t = 0; t < 4; t++) {
                uint32 w = (&u[q].x)[t];
                acc[2 * t]     += v[q] * __uint_as_float(w << 16);
                acc[2 * t + 1] += v[q] * __uint_as_float(w & 0xffff0000u);
            }
        }
    }

    // fold the EPG edge-subgroups: lanes with equal slot sum across sub
#pragma unroll
    for (int m = LPR; m < 64; m <<= 1) {
#pragma unroll
        for (int j = 0; j < 8; j++) acc[j] += __shfl_xor(acc[j], m);
    }

    if (RELU) {
#pragma unroll
        for (int j = 0; j < 8; j++) acc[j] = acc[j] > 0.f ? acc[j] : 0.f;
    }

    if (lane < LPR) {
        float4* o = (float4*)(out + (size_t)row * D + slot * 8);
        o[0] = make_float4(acc[0], acc[1], acc[2], acc[3]);
        o[1] = make_float4(acc[4], acc[5], acc[6], acc[7]);
    }
}

// ---------------- launch ----------------

extern "C" void kernel_launch(void* const* d_in, const int* in_sizes, int n_in,
                              void* d_out, int out_size, void* d_ws, size_t ws_size,
                              hipStream_t stream) {
    const float* x    = (const float*)d_in[0];
    const float* adj  = (const float*)d_in[1];
    const float* w1   = (const float*)d_in[2];
    const float* w2   = (const float*)d_in[3];
    const int*   esrc = (const int*)d_in[4];
    const int*   edst = (const int*)d_in[5];
    float* out = (float*)d_out;

    const int N = N_NODES;
    const int E = N_EDGES;

    char* ws = (char*)d_ws;
    size_t off = 0;
    auto take = [&](size_t bytes) -> char* {
        char* p = ws + off;
        off = (off + bytes + 255) & ~(size_t)255;
        return p;
    };
    int*      bcnt    = (int*)take((size_t)NBUCK * 4);
    int*      bptr    = (int*)take((size_t)(NBUCK + 1) * 4);
    int*      cursor  = (int*)take((size_t)NBUCK * 4);
    int*      row_ptr = (int*)take((size_t)(N + 1) * 4);
    int2*     part    = (int2*)take((size_t)E * 8);          // becomes row-sorted CSR
    ushort16* pre1    = (ushort16*)take((size_t)N * HIDDEN * 2);   // bf16
    ushort16* pre2    = (ushort16*)take((size_t)N * OUT_DIM * 2);  // bf16
    float*    h       = (float*)take((size_t)N * HIDDEN * 4);      // fp32
    unsigned short* w1f_hi = (unsigned short*)take((size_t)HIDDEN * IN_DIM * 2);
    unsigned short* w1f_lo = (unsigned short*)take((size_t)HIDDEN * IN_DIM * 2);
    unsigned short* w2f_hi = (unsigned short*)take((size_t)OUT_DIM * HIDDEN * 2);
    unsigned short* w2f_lo = (unsigned short*)take((size_t)OUT_DIM * HIDDEN * 2);

    // weight split to fragment-major (tiny)
    splitw_kernel<<<20, 256, 0, stream>>>(w1, w2, w1f_hi, w1f_lo, w2f_hi, w2f_lo);

    // CSR build: bucket partition -> per-bucket counting sort
    hipMemsetAsync(bcnt, 0, (size_t)NBUCK * 4, stream);
    hist_bucket<<<1024, 256, 0, stream>>>(edst, bcnt, E);
    bucket_scan<<<1, 256, 0, stream>>>(bcnt, bptr, cursor, row_ptr, E);
    partition_kernel<<<(E + CHUNK - 1) / CHUNK, 256, 0, stream>>>(esrc, edst, adj, cursor, part, E);
    bucket_to_csr<<<NBUCK, 256, 0, stream>>>(bptr, part, row_ptr);

    // Layer 1: pre1 = bf16(X@W1) via MFMA ; h = relu(A @ pre1) in fp32
    gemm_mfma<IN_DIM, HIDDEN><<<(N + 127) / 128, 256, 0, stream>>>(x, w1f_hi, w1f_lo, pre1, N);
    spmm_kernel<HIDDEN, true><<<(N + 3) / 4, 256, 0, stream>>>(pre1, part, row_ptr, h, N);

    // Layer 2: pre2 = bf16(h@W2) via MFMA ; out = A @ pre2 in fp32
    gemm_mfma<HIDDEN, OUT_DIM><<<(N + 127) / 128, 256, 0, stream>>>(h, w2f_hi, w2f_lo, pre2, N);
    spmm_kernel<OUT_DIM, false><<<(N + 3) / 4, 256, 0, stream>>>(pre2, part, row_ptr, out, N);
}

// Round 5
// 547.685 us; speedup vs baseline: 1.4012x; 1.0024x over previous
//
#include <hip/hip_runtime.h>

#define N_NODES 100000
#define N_EDGES 3200000
#define IN_DIM 256
#define HIDDEN 128
#define OUT_DIM 64

#define NBUCK 782        // ceil(100000 / 128) buckets of 128 dst rows
#define CHUNK 2560       // edges per partition block (1250 blocks, ~5/CU)
#define NPT (CHUNK / 256)
#define BCAP 6144        // max edges per bucket for LDS sort (mean 4096, sd 64)
#define CURSTRIDE 32     // pad cursor to one per 128B line

typedef unsigned int uint32;
typedef unsigned short ushort16;

typedef short short8 __attribute__((ext_vector_type(8)));   // 8 bf16 (4 VGPRs)
typedef float f32x4 __attribute__((ext_vector_type(4)));    // MFMA acc

// round-to-nearest-even f32 -> bf16
__device__ __forceinline__ ushort16 f2bf(float f) {
    uint32 u = __float_as_uint(f);
    u += 0x7fffu + ((u >> 16) & 1u);
    return (ushort16)(u >> 16);
}

// split f32 into bf16 hi + bf16 lo, f ~= hi + lo (error ~2^-16 rel)
__device__ __forceinline__ void splitbf(float f, unsigned short& hi, unsigned short& lo) {
    uint32 u = __float_as_uint(f);
    uint32 r = u + 0x7fffu + ((u >> 16) & 1u);
    hi = (unsigned short)(r >> 16);
    float hf = __uint_as_float((r >> 16) << 16);
    float res = f - hf;                    // exact (Sterbenz: same binade)
    uint32 v = __float_as_uint(res);
    lo = (unsigned short)((v + 0x7fffu + ((v >> 16) & 1u)) >> 16);
}

// ---------------- bucket histogram ----------------

__global__ __launch_bounds__(256)
void hist_bucket(const int* __restrict__ edst, int* __restrict__ bcnt, int E) {
    __shared__ int h[NBUCK];
    for (int b = threadIdx.x; b < NBUCK; b += 256) h[b] = 0;
    __syncthreads();
    for (int i = blockIdx.x * 256 + threadIdx.x; i < E; i += gridDim.x * 256)
        atomicAdd(&h[edst[i] >> 7], 1);
    __syncthreads();
    for (int b = threadIdx.x; b < NBUCK; b += 256) {
        int c = h[b];
        if (c) atomicAdd(&bcnt[b], c);
    }
}

// ---------------- bucket exclusive scan (one block) ----------------

__global__ __launch_bounds__(256)
void bucket_scan(const int* __restrict__ bcnt, int* __restrict__ bptr,
                 int* __restrict__ cursor, int* __restrict__ row_ptr, int E) {
    __shared__ int st[256];
    int tid = threadIdx.x;
    int v4[4];
    int s0 = 0;
#pragma unroll
    for (int k = 0; k < 4; k++) {
        int b = tid * 4 + k;
        v4[k] = (b < NBUCK) ? bcnt[b] : 0;
        s0 += v4[k];
    }
    st[tid] = s0;
    __syncthreads();
    for (int off = 1; off < 256; off <<= 1) {
        int t = (tid >= off) ? st[tid - off] : 0;
        __syncthreads();
        st[tid] += t;
        __syncthreads();
    }
    int run = st[tid] - s0;
#pragma unroll
    for (int k = 0; k < 4; k++) {
        int b = tid * 4 + k;
        if (b < NBUCK) { bptr[b] = run; cursor[b * CURSTRIDE] = run; }
        run += v4[k];
    }
    if (tid == 255) bptr[NBUCK] = run;
    if (tid == 0) row_ptr[N_NODES] = E;
}

// ---------------- partition: histogram + range-reserve + direct scatter ----------------
// No LDS staging, no prefix scan. Within-bucket order is arbitrary (bucket_to_csr
// re-sorts by row). part region is L2-resident, so scattered 8B writes are absorbed.
// payload p.x = src | (dst&127)<<17 ; p.y = val bits

__global__ __launch_bounds__(256)
void partition_kernel(const int* __restrict__ esrc, const int* __restrict__ edst,
                      const float* __restrict__ evals, int* __restrict__ cursor,
                      int2* __restrict__ part, int E) {
    __shared__ int hist[NBUCK];
    __shared__ int base_[NBUCK];
    int tid = threadIdx.x;
    long base = (long)blockIdx.x * CHUNK;
    int cnt = (int)min((long)CHUNK, (long)E - base);

    for (int b = tid; b < NBUCK; b += 256) hist[b] = 0;
    __syncthreads();

    int d[NPT];
#pragma unroll
    for (int k = 0; k < NPT; k++) {
        int j = tid + k * 256;                 // coalesced
        d[k] = -1;
        if (j < cnt) {
            d[k] = edst[base + j];
            atomicAdd(&hist[d[k] >> 7], 1);
        }
    }
    __syncthreads();

    for (int b = tid; b < NBUCK; b += 256) {
        int c = hist[b];
        base_[b] = c ? atomicAdd(&cursor[b * CURSTRIDE], c) : 0;
        hist[b] = 0;                           // reuse as chunk-local running cursor
    }
    __syncthreads();

#pragma unroll
    for (int k = 0; k < NPT; k++) {
        int j = tid + k * 256;
        if (j < cnt) {
            int dd = d[k], b = dd >> 7;
            int off2 = atomicAdd(&hist[b], 1);
            part[base_[b] + off2] = make_int2(esrc[base + j] | ((dd & 127) << 17),
                                              __float_as_int(evals[base + j]));
        }
    }
}

// ---------------- per-bucket counting sort -> row-sorted CSR (in place) ----------------

__global__ __launch_bounds__(256)
void bucket_to_csr(const int* __restrict__ bptr, int2* __restrict__ part,
                   int* __restrict__ row_ptr) {
    __shared__ int2 se[BCAP];
    __shared__ int rcnt[128];
    __shared__ int rcur[128];
    int tid = threadIdx.x;
    int b = blockIdx.x;
    int s = bptr[b], e = bptr[b + 1];
    int cnt = min(e - s, BCAP);

    if (tid < 128) rcnt[tid] = 0;
    __syncthreads();
    for (int j = tid; j < cnt; j += 256) {
        int2 p = part[s + j];
        se[j] = p;
        atomicAdd(&rcnt[p.x >> 17], 1);
    }
    __syncthreads();

    int v = (tid < 128) ? rcnt[tid] : 0;
    if (tid < 128) rcur[tid] = v;
    __syncthreads();
    for (int off = 1; off < 128; off <<= 1) {
        int t = 0;
        if (tid < 128 && tid >= off) t = rcur[tid - off];
        __syncthreads();
        if (tid < 128 && tid >= off) rcur[tid] += t;
        __syncthreads();
    }
    if (tid < 128) {
        int excl = rcur[tid] - v;
        rcur[tid] = excl;
        int row = b * 128 + tid;
        if (row < N_NODES) row_ptr[row] = s + excl;
    }
    __syncthreads();

    for (int j = tid; j < cnt; j += 256) {
        int2 p = se[j];
        int r = p.x >> 17;
        int pos = atomicAdd(&rcur[r], 1);
        part[s + pos] = make_int2(p.x & 0x1FFFF, p.y);
    }
}

// ---------------- weight split to MFMA-fragment-major layout (tiny, once) ----------------
// Layout: [kblk][nfrag][lane][8]  with  n = nfrag*16 + (lane&15), k = kblk*32 + (lane>>4)*8 + j
// -> a wave's fragment load is base + lane*16B: one coalesced 1KB load per instruction.

__global__ __launch_bounds__(256)
void splitw_kernel(const float* __restrict__ w1, const float* __restrict__ w2,
                   unsigned short* __restrict__ w1f_hi, unsigned short* __restrict__ w1f_lo,
                   unsigned short* __restrict__ w2f_hi, unsigned short* __restrict__ w2f_lo) {
    const int W1_SLOTS = (IN_DIM / 32) * (HIDDEN / 16) * 64;   // 8*8*64 = 4096
    const int W2_SLOTS = (HIDDEN / 32) * (OUT_DIM / 16) * 64;  // 4*4*64 = 1024
    int g = blockIdx.x * 256 + threadIdx.x;
    if (g < W1_SLOTS) {
        int lane = g & 63;
        int rest = g >> 6;
        int nfrag = rest & 7;              // HIDDEN/16 = 8
        int kblk = rest >> 3;
        int n = nfrag * 16 + (lane & 15);
        int k0 = kblk * 32 + (lane >> 4) * 8;
#pragma unroll
        for (int j = 0; j < 8; j++) {
            unsigned short h, l;
            splitbf(w1[(size_t)(k0 + j) * HIDDEN + n], h, l);
            w1f_hi[(size_t)g * 8 + j] = h;
            w1f_lo[(size_t)g * 8 + j] = l;
        }
    } else if (g < W1_SLOTS + W2_SLOTS) {
        int g2 = g - W1_SLOTS;
        int lane = g2 & 63;
        int rest = g2 >> 6;
        int nfrag = rest & 3;              // OUT_DIM/16 = 4
        int kblk = rest >> 2;
        int n = nfrag * 16 + (lane & 15);
        int k0 = kblk * 32 + (lane >> 4) * 8;
#pragma unroll
        for (int j = 0; j < 8; j++) {
            unsigned short h, l;
            splitbf(w2[(size_t)(k0 + j) * OUT_DIM + n], h, l);
            w2f_hi[(size_t)g2 * 8 + j] = h;
            w2f_lo[(size_t)g2 * 8 + j] = l;
        }
    }
}

// ---------------- MFMA GEMM: C(bf16) = A(fp32) @ B, split-bf16 3-product ----------------
// B in fragment-major layout (see splitw_kernel): coalesced lane*16B loads.

template <int K, int BN>
__launch_bounds__(256)
__global__ void gemm_mfma(const float* __restrict__ A,
                          const unsigned short* __restrict__ Bf_hi,
                          const unsigned short* __restrict__ Bf_lo,
                          ushort16* __restrict__ C, int M) {
    constexpr int BM = 128, BK = 64;
    constexpr int NF = BN / 32;              // n-frags per wave (wave n-span = BN/2)
    __shared__ __align__(16) unsigned short Ah[BM * BK];
    __shared__ __align__(16) unsigned short Al[BM * BK];

    int tid = threadIdx.x;
    int wid = tid >> 6, lane = tid & 63;
    int wr = wid >> 1, wc = wid & 1;         // wave row/col in 2x2
    int rowBase = blockIdx.x * BM;
    int r = lane & 15, kg = lane >> 4;       // frag row(col) index, k-group
    int swzmask = (lane & 7) << 4;           // == (r&7)<<4

    f32x4 zero = {0.f, 0.f, 0.f, 0.f};
    f32x4 acc[4][NF];
#pragma unroll
    for (int m = 0; m < 4; m++)
#pragma unroll
        for (int n = 0; n < NF; n++) acc[m][n] = zero;

    int sk4 = (tid & 15) * 4;
    int sm0 = tid >> 4;

    for (int k0 = 0; k0 < K; k0 += BK) {
#pragma unroll
        for (int i = 0; i < 8; i++) {
            int m = sm0 + i * 16;
            int row = rowBase + m;
            float4 f = make_float4(0.f, 0.f, 0.f, 0.f);
            if (row < M) f = *(const float4*)(A + (size_t)row * K + k0 + sk4);
            ushort4 h, l;
            splitbf(f.x, h.x, l.x);
            splitbf(f.y, h.y, l.y);
            splitbf(f.z, h.z, l.z);
            splitbf(f.w, h.w, l.w);
            int bo = (m * BK + sk4) * 2;
            int swz = bo ^ ((m & 7) << 4);
            *(ushort4*)((char*)Ah + swz) = h;
            *(ushort4*)((char*)Al + swz) = l;
        }
        __syncthreads();

#pragma unroll
        for (int kk = 0; kk < BK / 32; kk++) {
            short8 ah[4], al[4];
            int abase = (wr * 64 + r) * (BK * 2) + kk * 64 + kg * 16;
#pragma unroll
            for (int m = 0; m < 4; m++) {
                int swz = (abase + m * (16 * BK * 2)) ^ swzmask;
                ah[m] = *(const short8*)((const char*)Ah + swz);
                al[m] = *(const short8*)((const char*)Al + swz);
            }
            short8 bh[NF], bl[NF];
            int kblk = (k0 >> 5) + kk;
#pragma unroll
            for (int n = 0; n < NF; n++) {
                int nf = wc * NF + n;
                size_t off = ((size_t)(kblk * (BN / 16) + nf) * 64 + lane) * 8;
                bh[n] = *(const short8*)(Bf_hi + off);
                bl[n] = *(const short8*)(Bf_lo + off);
            }
#pragma unroll
            for (int m = 0; m < 4; m++)
#pragma unroll
                for (int n = 0; n < NF; n++) {
                    acc[m][n] = __builtin_amdgcn_mfma_f32_16x16x32_bf16(ah[m], bh[n], acc[m][n], 0, 0, 0);
                    acc[m][n] = __builtin_amdgcn_mfma_f32_16x16x32_bf16(ah[m], bl[n], acc[m][n], 0, 0, 0);
                    acc[m][n] = __builtin_amdgcn_mfma_f32_16x16x32_bf16(al[m], bh[n], acc[m][n], 0, 0, 0);
                }
        }
        __syncthreads();
    }

#pragma unroll
    for (int m = 0; m < 4; m++) {
        int row0 = rowBase + wr * 64 + m * 16 + kg * 4;
#pragma unroll
        for (int j = 0; j < 4; j++) {
            int row = row0 + j;
            if (row < M) {
#pragma unroll
                for (int n = 0; n < NF; n++) {
                    int col = wc * (BN / 2) + n * 16 + r;
                    C[(size_t)row * BN + col] = f2bf(acc[m][n][j]);
                }
            }
        }
    }
}

// ---------------- SpMM: wave per dst row, multi-edge-per-gather, 4-deep pipeline ----------------
// Lane map: slot = lane % LPR covers the row's 16B chunks (LPR*16B = D*2B = full row),
//           sub  = lane / LPR selects which edge this lane serves (EPG edges per gather).
// One global_load_dwordx4 fetches EPG edge-rows; 4 gathers kept in flight per wave.

template <int D, bool RELU>
__launch_bounds__(256)
__global__ void spmm_kernel(const ushort16* __restrict__ feat, const int2* __restrict__ csr_pair,
                            const int* __restrict__ row_ptr, float* __restrict__ out, int n) {
    constexpr int LPR = D * 2 / 16;      // lanes per row: 16 (D=128) or 8 (D=64)
    constexpr int EPG = 64 / LPR;        // edges per gather: 4 or 8
    int wid = threadIdx.x >> 6;
    int lane = threadIdx.x & 63;
    int row = blockIdx.x * 4 + wid;
    if (row >= n) return;
    int s = row_ptr[row], e = row_ptr[row + 1];

    int sub = lane / LPR;
    int slot = lane % LPR;
    const char* fbase = (const char*)feat + slot * 16;

    float acc[8];
#pragma unroll
    for (int j = 0; j < 8; j++) acc[j] = 0.f;

    for (int i = s; i < e; i += 4 * EPG) {
        int2 p[4]; float v[4]; uint4 u[4];
#pragma unroll
        for (int q = 0; q < 4; q++) {
            int ii = i + q * EPG + sub;
            p[q] = csr_pair[min(ii, e - 1)];
            v[q] = (ii < e) ? __int_as_float(p[q].y) : 0.f;
        }
#pragma unroll
        for (int q = 0; q < 4; q++)
            u[q] = *(const uint4*)(fbase + (size_t)p[q].x * (D * 2));
#pragma unroll
        for (int q = 0; q < 4; q++) {
#pragma unroll
            for (int t = 0; t < 4; t++) {
                uint32 w = (&u[q].x)[t];
                acc[2 * t]     += v[q] * __uint_as_float(w << 16);
                acc[2 * t + 1] += v[q] * __uint_as_float(w & 0xffff0000u);
            }
        }
    }

    // fold the EPG edge-subgroups: lanes with equal slot sum across sub
#pragma unroll
    for (int m = LPR; m < 64; m <<= 1) {
#pragma unroll
        for (int j = 0; j < 8; j++) acc[j] += __shfl_xor(acc[j], m);
    }

    if (RELU) {
#pragma unroll
        for (int j = 0; j < 8; j++) acc[j] = acc[j] > 0.f ? acc[j] : 0.f;
    }

    if (lane < LPR) {
        float4* o = (float4*)(out + (size_t)row * D + slot * 8);
        o[0] = make_float4(acc[0], acc[1], acc[2], acc[3]);
        o[1] = make_float4(acc[4], acc[5], acc[6], acc[7]);
    }
}

// ---------------- launch ----------------

extern "C" void kernel_launch(void* const* d_in, const int* in_sizes, int n_in,
                              void* d_out, int out_size, void* d_ws, size_t ws_size,
                              hipStream_t stream) {
    const float* x    = (const float*)d_in[0];
    const float* adj  = (const float*)d_in[1];
    const float* w1   = (const float*)d_in[2];
    const float* w2   = (const float*)d_in[3];
    const int*   esrc = (const int*)d_in[4];
    const int*   edst = (const int*)d_in[5];
    float* out = (float*)d_out;

    const int N = N_NODES;
    const int E = N_EDGES;

    char* ws = (char*)d_ws;
    size_t off = 0;
    auto take = [&](size_t bytes) -> char* {
        char* p = ws + off;
        off = (off + bytes + 255) & ~(size_t)255;
        return p;
    };
    int*      bcnt    = (int*)take((size_t)NBUCK * 4);
    int*      bptr    = (int*)take((size_t)(NBUCK + 1) * 4);
    int*      cursor  = (int*)take((size_t)NBUCK * CURSTRIDE * 4);   // 128B-padded
    int*      row_ptr = (int*)take((size_t)(N + 1) * 4);
    int2*     part    = (int2*)take((size_t)E * 8);          // becomes row-sorted CSR
    ushort16* pre1    = (ushort16*)take((size_t)N * HIDDEN * 2);   // bf16
    ushort16* pre2    = (ushort16*)take((size_t)N * OUT_DIM * 2);  // bf16
    float*    h       = (float*)take((size_t)N * HIDDEN * 4);      // fp32
    unsigned short* w1f_hi = (unsigned short*)take((size_t)HIDDEN * IN_DIM * 2);
    unsigned short* w1f_lo = (unsigned short*)take((size_t)HIDDEN * IN_DIM * 2);
    unsigned short* w2f_hi = (unsigned short*)take((size_t)OUT_DIM * HIDDEN * 2);
    unsigned short* w2f_lo = (unsigned short*)take((size_t)OUT_DIM * HIDDEN * 2);

    // weight split to fragment-major (tiny)
    splitw_kernel<<<20, 256, 0, stream>>>(w1, w2, w1f_hi, w1f_lo, w2f_hi, w2f_lo);

    // CSR build: bucket partition -> per-bucket counting sort
    hipMemsetAsync(bcnt, 0, (size_t)NBUCK * 4, stream);
    hist_bucket<<<1024, 256, 0, stream>>>(edst, bcnt, E);
    bucket_scan<<<1, 256, 0, stream>>>(bcnt, bptr, cursor, row_ptr, E);
    partition_kernel<<<(E + CHUNK - 1) / CHUNK, 256, 0, stream>>>(esrc, edst, adj, cursor, part, E);
    bucket_to_csr<<<NBUCK, 256, 0, stream>>>(bptr, part, row_ptr);

    // Layer 1: pre1 = bf16(X@W1) via MFMA ; h = relu(A @ pre1) in fp32
    gemm_mfma<IN_DIM, HIDDEN><<<(N + 127) / 128, 256, 0, stream>>>(x, w1f_hi, w1f_lo, pre1, N);
    spmm_kernel<HIDDEN, true><<<(N + 3) / 4, 256, 0, stream>>>(pre1, part, row_ptr, h, N);

    // Layer 2: pre2 = bf16(h@W2) via MFMA ; out = A @ pre2 in fp32
    gemm_mfma<HIDDEN, OUT_DIM><<<(N + 127) / 128, 256, 0, stream>>>(h, w2f_hi, w2f_lo, pre2, N);
    spmm_kernel<OUT_DIM, false><<<(N + 3) / 4, 256, 0, stream>>>(pre2, part, row_ptr, out, N);
}

// Round 6
// 501.675 us; speedup vs baseline: 1.5297x; 1.0917x over previous
//
#include <hip/hip_runtime.h>

#define N_NODES 100000
#define N_EDGES 3200000
#define IN_DIM 256
#define HIDDEN 128
#define OUT_DIM 64

#define NBUCK 782        // ceil(100000 / 128) buckets of 128 dst rows
#define CHUNK 3072       // edges per partition block
#define NPT (CHUNK / 256)
#define NPB ((N_EDGES + CHUNK - 1) / CHUNK)   // 1042 partition blocks
#define BCAP 6144        // max edges per bucket for LDS sort (mean 4096, sd 64)
#define CURSTRIDE 32     // pad cursor to one per 128B line

typedef unsigned int uint32;
typedef unsigned short ushort16;

typedef short short8 __attribute__((ext_vector_type(8)));   // 8 bf16 (4 VGPRs)
typedef float f32x4 __attribute__((ext_vector_type(4)));    // MFMA acc

// round-to-nearest-even f32 -> bf16
__device__ __forceinline__ ushort16 f2bf(float f) {
    uint32 u = __float_as_uint(f);
    u += 0x7fffu + ((u >> 16) & 1u);
    return (ushort16)(u >> 16);
}

// split f32 into bf16 hi + bf16 lo, f ~= hi + lo (error ~2^-16 rel)
__device__ __forceinline__ void splitbf(float f, unsigned short& hi, unsigned short& lo) {
    uint32 u = __float_as_uint(f);
    uint32 r = u + 0x7fffu + ((u >> 16) & 1u);
    hi = (unsigned short)(r >> 16);
    float hf = __uint_as_float((r >> 16) << 16);
    float res = f - hf;                    // exact (Sterbenz: same binade)
    uint32 v = __float_as_uint(res);
    lo = (unsigned short)((v + 0x7fffu + ((v >> 16) & 1u)) >> 16);
}

// ---------------- bucket histogram ----------------

__global__ __launch_bounds__(256)
void hist_bucket(const int* __restrict__ edst, int* __restrict__ bcnt, int E) {
    __shared__ int h[NBUCK];
    for (int b = threadIdx.x; b < NBUCK; b += 256) h[b] = 0;
    __syncthreads();
    for (int i = blockIdx.x * 256 + threadIdx.x; i < E; i += gridDim.x * 256)
        atomicAdd(&h[edst[i] >> 7], 1);
    __syncthreads();
    for (int b = threadIdx.x; b < NBUCK; b += 256) {
        int c = h[b];
        if (c) atomicAdd(&bcnt[b], c);
    }
}

// ---------------- bucket exclusive scan (one block) ----------------

__global__ __launch_bounds__(256)
void bucket_scan(const int* __restrict__ bcnt, int* __restrict__ bptr,
                 int* __restrict__ cursor, int* __restrict__ row_ptr, int E) {
    __shared__ int st[256];
    int tid = threadIdx.x;
    int v4[4];
    int s0 = 0;
#pragma unroll
    for (int k = 0; k < 4; k++) {
        int b = tid * 4 + k;
        v4[k] = (b < NBUCK) ? bcnt[b] : 0;
        s0 += v4[k];
    }
    st[tid] = s0;
    __syncthreads();
    for (int off = 1; off < 256; off <<= 1) {
        int t = (tid >= off) ? st[tid - off] : 0;
        __syncthreads();
        st[tid] += t;
        __syncthreads();
    }
    int run = st[tid] - s0;
#pragma unroll
    for (int k = 0; k < 4; k++) {
        int b = tid * 4 + k;
        if (b < NBUCK) { bptr[b] = run; cursor[b * CURSTRIDE] = run; }
        run += v4[k];
    }
    if (tid == 255) bptr[NBUCK] = run;
    if (tid == 0) row_ptr[N_NODES] = E;
}

// ---------------- per-bucket counting sort -> row-sorted CSR (in place) ----------------

__global__ __launch_bounds__(256)
void bucket_to_csr(const int* __restrict__ bptr, int2* __restrict__ part,
                   int* __restrict__ row_ptr) {
    __shared__ int2 se[BCAP];
    __shared__ int rcnt[128];
    __shared__ int rcur[128];
    int tid = threadIdx.x;
    int b = blockIdx.x;
    int s = bptr[b], e = bptr[b + 1];
    int cnt = min(e - s, BCAP);

    if (tid < 128) rcnt[tid] = 0;
    __syncthreads();
    for (int j = tid; j < cnt; j += 256) {
        int2 p = part[s + j];
        se[j] = p;
        atomicAdd(&rcnt[p.x >> 17], 1);
    }
    __syncthreads();

    int v = (tid < 128) ? rcnt[tid] : 0;
    if (tid < 128) rcur[tid] = v;
    __syncthreads();
    for (int off = 1; off < 128; off <<= 1) {
        int t = 0;
        if (tid < 128 && tid >= off) t = rcur[tid - off];
        __syncthreads();
        if (tid < 128 && tid >= off) rcur[tid] += t;
        __syncthreads();
    }
    if (tid < 128) {
        int excl = rcur[tid] - v;
        rcur[tid] = excl;
        int row = b * 128 + tid;
        if (row < N_NODES) row_ptr[row] = s + excl;
    }
    __syncthreads();

    for (int j = tid; j < cnt; j += 256) {
        int2 p = se[j];
        int r = p.x >> 17;
        int pos = atomicAdd(&rcur[r], 1);
        part[s + pos] = make_int2(p.x & 0x1FFFF, p.y);
    }
}

// ---------------- weight split to MFMA-fragment-major layout (tiny, once) ----------------
// Layout: [kblk][nfrag][lane][8]  with  n = nfrag*16 + (lane&15), k = kblk*32 + (lane>>4)*8 + j

__global__ __launch_bounds__(256)
void splitw_kernel(const float* __restrict__ w1, const float* __restrict__ w2,
                   unsigned short* __restrict__ w1f_hi, unsigned short* __restrict__ w1f_lo,
                   unsigned short* __restrict__ w2f_hi, unsigned short* __restrict__ w2f_lo) {
    const int W1_SLOTS = (IN_DIM / 32) * (HIDDEN / 16) * 64;   // 4096
    const int W2_SLOTS = (HIDDEN / 32) * (OUT_DIM / 16) * 64;  // 1024
    int g = blockIdx.x * 256 + threadIdx.x;
    if (g < W1_SLOTS) {
        int lane = g & 63;
        int rest = g >> 6;
        int nfrag = rest & 7;              // HIDDEN/16 = 8
        int kblk = rest >> 3;
        int n = nfrag * 16 + (lane & 15);
        int k0 = kblk * 32 + (lane >> 4) * 8;
#pragma unroll
        for (int j = 0; j < 8; j++) {
            unsigned short h, l;
            splitbf(w1[(size_t)(k0 + j) * HIDDEN + n], h, l);
            w1f_hi[(size_t)g * 8 + j] = h;
            w1f_lo[(size_t)g * 8 + j] = l;
        }
    } else if (g < W1_SLOTS + W2_SLOTS) {
        int g2 = g - W1_SLOTS;
        int lane = g2 & 63;
        int rest = g2 >> 6;
        int nfrag = rest & 3;              // OUT_DIM/16 = 4
        int kblk = rest >> 2;
        int n = nfrag * 16 + (lane & 15);
        int k0 = kblk * 32 + (lane >> 4) * 8;
#pragma unroll
        for (int j = 0; j < 8; j++) {
            unsigned short h, l;
            splitbf(w2[(size_t)(k0 + j) * OUT_DIM + n], h, l);
            w2f_hi[(size_t)g2 * 8 + j] = h;
            w2f_lo[(size_t)g2 * 8 + j] = l;
        }
    }
}

// ---------------- MFMA GEMM body (device fn): C(bf16) = A(fp32) @ B, split-bf16 3-product ----

template <int K, int BN>
__device__ __forceinline__ void gemm_body(int bx, char* smem, const float* __restrict__ A,
                                          const unsigned short* __restrict__ Bf_hi,
                                          const unsigned short* __restrict__ Bf_lo,
                                          ushort16* __restrict__ C, int M) {
    constexpr int BM = 128, BK = 64;
    constexpr int NF = BN / 32;
    unsigned short* Ah = (unsigned short*)smem;                 // 16384 B
    unsigned short* Al = (unsigned short*)(smem + BM * BK * 2); // 16384 B

    int tid = threadIdx.x;
    int wid = tid >> 6, lane = tid & 63;
    int wr = wid >> 1, wc = wid & 1;
    int rowBase = bx * BM;
    int r = lane & 15, kg = lane >> 4;
    int swzmask = (lane & 7) << 4;

    f32x4 zero = {0.f, 0.f, 0.f, 0.f};
    f32x4 acc[4][NF];
#pragma unroll
    for (int m = 0; m < 4; m++)
#pragma unroll
        for (int n = 0; n < NF; n++) acc[m][n] = zero;

    int sk4 = (tid & 15) * 4;
    int sm0 = tid >> 4;

    for (int k0 = 0; k0 < K; k0 += BK) {
#pragma unroll
        for (int i = 0; i < 8; i++) {
            int m = sm0 + i * 16;
            int row = rowBase + m;
            float4 f = make_float4(0.f, 0.f, 0.f, 0.f);
            if (row < M) f = *(const float4*)(A + (size_t)row * K + k0 + sk4);
            ushort4 h, l;
            splitbf(f.x, h.x, l.x);
            splitbf(f.y, h.y, l.y);
            splitbf(f.z, h.z, l.z);
            splitbf(f.w, h.w, l.w);
            int bo = (m * BK + sk4) * 2;
            int swz = bo ^ ((m & 7) << 4);
            *(ushort4*)((char*)Ah + swz) = h;
            *(ushort4*)((char*)Al + swz) = l;
        }
        __syncthreads();

#pragma unroll
        for (int kk = 0; kk < BK / 32; kk++) {
            short8 ah[4], al[4];
            int abase = (wr * 64 + r) * (BK * 2) + kk * 64 + kg * 16;
#pragma unroll
            for (int m = 0; m < 4; m++) {
                int swz = (abase + m * (16 * BK * 2)) ^ swzmask;
                ah[m] = *(const short8*)((const char*)Ah + swz);
                al[m] = *(const short8*)((const char*)Al + swz);
            }
            short8 bh[NF], bl[NF];
            int kblk = (k0 >> 5) + kk;
#pragma unroll
            for (int n = 0; n < NF; n++) {
                int nf = wc * NF + n;
                size_t off = ((size_t)(kblk * (BN / 16) + nf) * 64 + lane) * 8;
                bh[n] = *(const short8*)(Bf_hi + off);
                bl[n] = *(const short8*)(Bf_lo + off);
            }
#pragma unroll
            for (int m = 0; m < 4; m++)
#pragma unroll
                for (int n = 0; n < NF; n++) {
                    acc[m][n] = __builtin_amdgcn_mfma_f32_16x16x32_bf16(ah[m], bh[n], acc[m][n], 0, 0, 0);
                    acc[m][n] = __builtin_amdgcn_mfma_f32_16x16x32_bf16(ah[m], bl[n], acc[m][n], 0, 0, 0);
                    acc[m][n] = __builtin_amdgcn_mfma_f32_16x16x32_bf16(al[m], bh[n], acc[m][n], 0, 0, 0);
                }
        }
        __syncthreads();
    }

#pragma unroll
    for (int m = 0; m < 4; m++) {
        int row0 = rowBase + wr * 64 + m * 16 + kg * 4;
#pragma unroll
        for (int j = 0; j < 4; j++) {
            int row = row0 + j;
            if (row < M) {
#pragma unroll
                for (int n = 0; n < NF; n++) {
                    int col = wc * (BN / 2) + n * 16 + r;
                    C[(size_t)row * BN + col] = f2bf(acc[m][n][j]);
                }
            }
        }
    }
}

// standalone GEMM kernel (layer 2)
template <int K, int BN>
__launch_bounds__(256)
__global__ void gemm_mfma(const float* __restrict__ A,
                          const unsigned short* __restrict__ Bf_hi,
                          const unsigned short* __restrict__ Bf_lo,
                          ushort16* __restrict__ C, int M) {
    __shared__ __align__(16) char smem[32768];
    gemm_body<K, BN>(blockIdx.x, smem, A, Bf_hi, Bf_lo, C, M);
}

// ---------------- fused: partition (blocks < NPB) + gemm1 (blocks >= NPB) ----------------
// Partition v3: LDS staged counting sort per chunk, single-wave shfl scan (no 16-barrier
// block scan), atomic range-reserve (no global ordering), register-stashed src/dst/val.
// Dump phase writes bucket-grouped runs (~4 edges = 32B) -> 4x fewer write transactions
// than fully-scattered. gemm1 blocks backfill CUs and hide partition's memory latency.

__launch_bounds__(256)
__global__ void partition_gemm1(const int* __restrict__ esrc, const int* __restrict__ edst,
                                const float* __restrict__ evals, int* __restrict__ cursor,
                                int2* __restrict__ part, int E,
                                const float* __restrict__ A,
                                const unsigned short* __restrict__ w1f_hi,
                                const unsigned short* __restrict__ w1f_lo,
                                ushort16* __restrict__ pre1, int M) {
    __shared__ __align__(16) char smem[40960];
    if (blockIdx.x >= NPB) {
        gemm_body<IN_DIM, HIDDEN>(blockIdx.x - NPB, smem, A, w1f_hi, w1f_lo, pre1, M);
        return;
    }
    // --- partition side ---
    int2* sbp  = (int2*)smem;                        // [0, 24576)
    unsigned short* sbb = (unsigned short*)(smem + 24576);   // [24576, 30720)
    int* hist  = (int*)(smem + 30720);               // [30720, 33848) - counts, then cursor
    int* lst   = (int*)(smem + 33848);               // chunk-local exclusive start
    int* bpos  = (int*)(smem + 36976);               // global base - local start

    int tid = threadIdx.x;
    long base = (long)blockIdx.x * CHUNK;
    int cnt = (int)min((long)CHUNK, (long)E - base);

    for (int b = tid; b < NBUCK; b += 256) hist[b] = 0;
    __syncthreads();

    int d[NPT], sv[NPT]; float vv[NPT];
#pragma unroll
    for (int k = 0; k < NPT; k++) {
        int j = tid + k * 256;
        d[k] = -1;
        if (j < cnt) {
            d[k]  = edst[base + j];
            sv[k] = esrc[base + j];
            vv[k] = evals[base + j];
            atomicAdd(&hist[d[k] >> 7], 1);
        }
    }
    __syncthreads();

    // single-wave exclusive scan over 782 buckets (13 per lane)
    if (tid < 64) {
        int c[13];
        int run = 0;
#pragma unroll
        for (int k = 0; k < 13; k++) {
            int b = tid * 13 + k;
            c[k] = (b < NBUCK) ? hist[b] : 0;
            run += c[k];
        }
        int sum = run;
#pragma unroll
        for (int off = 1; off < 64; off <<= 1) {
            int up = __shfl_up(sum, off);
            if (tid >= off) sum += up;
        }
        int excl = sum - run;
#pragma unroll
        for (int k = 0; k < 13; k++) {
            int b = tid * 13 + k;
            if (b < NBUCK) lst[b] = excl;
            excl += c[k];
        }
    }
    __syncthreads();

    // range-reserve in global cursor; hist becomes the chunk-local running cursor
    for (int b = tid; b < NBUCK; b += 256) {
        int c = hist[b];
        int g = c ? atomicAdd(&cursor[b * CURSTRIDE], c) : 0;
        bpos[b] = g - lst[b];
        hist[b] = lst[b];
    }
    __syncthreads();

    // staged sort into LDS (bucket-grouped)
#pragma unroll
    for (int k = 0; k < NPT; k++) {
        int j = tid + k * 256;
        if (j < cnt) {
            int dd = d[k], b = dd >> 7;
            int pos = atomicAdd(&hist[b], 1);
            sbb[pos] = (unsigned short)b;
            sbp[pos] = make_int2(sv[k] | ((dd & 127) << 17), __float_as_int(vv[k]));
        }
    }
    __syncthreads();

    // dump: consecutive j in same bucket -> consecutive global addresses
    for (int j = tid; j < cnt; j += 256)
        part[bpos[sbb[j]] + j] = sbp[j];
}

// ---------------- SpMM: wave per dst row, multi-edge-per-gather, 4-deep pipeline ----------------

template <int D, bool RELU>
__launch_bounds__(256)
__global__ void spmm_kernel(const ushort16* __restrict__ feat, const int2* __restrict__ csr_pair,
                            const int* __restrict__ row_ptr, float* __restrict__ out, int n) {
    constexpr int LPR = D * 2 / 16;      // lanes per row: 16 (D=128) or 8 (D=64)
    constexpr int EPG = 64 / LPR;        // edges per gather: 4 or 8
    int wid = threadIdx.x >> 6;
    int lane = threadIdx.x & 63;
    int row = blockIdx.x * 4 + wid;
    if (row >= n) return;
    int s = row_ptr[row], e = row_ptr[row + 1];

    int sub = lane / LPR;
    int slot = lane % LPR;
    const char* fbase = (const char*)feat + slot * 16;

    float acc[8];
#pragma unroll
    for (int j = 0; j < 8; j++) acc[j] = 0.f;

    for (int i = s; i < e; i += 4 * EPG) {
        int2 p[4]; float v[4]; uint4 u[4];
#pragma unroll
        for (int q = 0; q < 4; q++) {
            int ii = i + q * EPG + sub;
            p[q] = csr_pair[min(ii, e - 1)];
            v[q] = (ii < e) ? __int_as_float(p[q].y) : 0.f;
        }
#pragma unroll
        for (int q = 0; q < 4; q++)
            u[q] = *(const uint4*)(fbase + (size_t)p[q].x * (D * 2));
#pragma unroll
        for (int q = 0; q < 4; q++) {
#pragma unroll
            for (int t = 0; t < 4; t++) {
                uint32 w = (&u[q].x)[t];
                acc[2 * t]     += v[q] * __uint_as_float(w << 16);
                acc[2 * t + 1] += v[q] * __uint_as_float(w & 0xffff0000u);
            }
        }
    }

#pragma unroll
    for (int m = LPR; m < 64; m <<= 1) {
#pragma unroll
        for (int j = 0; j < 8; j++) acc[j] += __shfl_xor(acc[j], m);
    }

    if (RELU) {
#pragma unroll
        for (int j = 0; j < 8; j++) acc[j] = acc[j] > 0.f ? acc[j] : 0.f;
    }

    if (lane < LPR) {
        float4* o = (float4*)(out + (size_t)row * D + slot * 8);
        o[0] = make_float4(acc[0], acc[1], acc[2], acc[3]);
        o[1] = make_float4(acc[4], acc[5], acc[6], acc[7]);
    }
}

// ---------------- launch ----------------

extern "C" void kernel_launch(void* const* d_in, const int* in_sizes, int n_in,
                              void* d_out, int out_size, void* d_ws, size_t ws_size,
                              hipStream_t stream) {
    const float* x    = (const float*)d_in[0];
    const float* adj  = (const float*)d_in[1];
    const float* w1   = (const float*)d_in[2];
    const float* w2   = (const float*)d_in[3];
    const int*   esrc = (const int*)d_in[4];
    const int*   edst = (const int*)d_in[5];
    float* out = (float*)d_out;

    const int N = N_NODES;
    const int E = N_EDGES;

    char* ws = (char*)d_ws;
    size_t off = 0;
    auto take = [&](size_t bytes) -> char* {
        char* p = ws + off;
        off = (off + bytes + 255) & ~(size_t)255;
        return p;
    };
    int*      bcnt    = (int*)take((size_t)NBUCK * 4);
    int*      bptr    = (int*)take((size_t)(NBUCK + 1) * 4);
    int*      cursor  = (int*)take((size_t)NBUCK * CURSTRIDE * 4);   // 128B-padded
    int*      row_ptr = (int*)take((size_t)(N + 1) * 4);
    int2*     part    = (int2*)take((size_t)E * 8);          // becomes row-sorted CSR
    ushort16* pre1    = (ushort16*)take((size_t)N * HIDDEN * 2);   // bf16
    ushort16* pre2    = (ushort16*)take((size_t)N * OUT_DIM * 2);  // bf16
    float*    h       = (float*)take((size_t)N * HIDDEN * 4);      // fp32
    unsigned short* w1f_hi = (unsigned short*)take((size_t)HIDDEN * IN_DIM * 2);
    unsigned short* w1f_lo = (unsigned short*)take((size_t)HIDDEN * IN_DIM * 2);
    unsigned short* w2f_hi = (unsigned short*)take((size_t)OUT_DIM * HIDDEN * 2);
    unsigned short* w2f_lo = (unsigned short*)take((size_t)OUT_DIM * HIDDEN * 2);

    // weight split to fragment-major (tiny)
    splitw_kernel<<<20, 256, 0, stream>>>(w1, w2, w1f_hi, w1f_lo, w2f_hi, w2f_lo);

    // CSR build prologue
    hipMemsetAsync(bcnt, 0, (size_t)NBUCK * 4, stream);
    hist_bucket<<<1024, 256, 0, stream>>>(edst, bcnt, E);
    bucket_scan<<<1, 256, 0, stream>>>(bcnt, bptr, cursor, row_ptr, E);

    // Fused: partition (1042 blocks) + gemm1 pre1 = bf16(X@W1) (782 blocks)
    partition_gemm1<<<NPB + (N_NODES + 127) / 128, 256, 0, stream>>>(
        esrc, edst, adj, cursor, part, E, x, w1f_hi, w1f_lo, pre1, N);

    bucket_to_csr<<<NBUCK, 256, 0, stream>>>(bptr, part, row_ptr);

    // Layer 1 SpMM: h = relu(A @ pre1) in fp32
    spmm_kernel<HIDDEN, true><<<(N + 3) / 4, 256, 0, stream>>>(pre1, part, row_ptr, h, N);

    // Layer 2: pre2 = bf16(h@W2) via MFMA ; out = A @ pre2 in fp32
    gemm_mfma<HIDDEN, OUT_DIM><<<(N + 127) / 128, 256, 0, stream>>>(h, w2f_hi, w2f_lo, pre2, N);
    spmm_kernel<OUT_DIM, false><<<(N + 3) / 4, 256, 0, stream>>>(pre2, part, row_ptr, out, N);
}

// Round 7
// 488.085 us; speedup vs baseline: 1.5723x; 1.0278x over previous
//
#include <hip/hip_runtime.h>

#define N_NODES 100000
#define N_EDGES 3200000
#define IN_DIM 256
#define HIDDEN 128
#define OUT_DIM 64

#define NBUCK 782        // ceil(100000 / 128) buckets of 128 dst rows
#define CHUNK 3072       // edges per partition block
#define NPT (CHUNK / 256)
#define NPB ((N_EDGES + CHUNK - 1) / CHUNK)   // 1042 pass-1 blocks
#define BCAP 6144        // max edges per bucket for LDS sort (mean 4096, sd 64)
#define CURSTRIDE 32     // pad cursors to one per 128B line
#define NCG 13           // coarse groups: dst>>13 (100000>>13 = 12)
#define CGBITS 13
#define MAXCH 92         // max chunks per coarse group (262K mean / 3072 = 85.3)

typedef unsigned int uint32;
typedef unsigned short ushort16;

typedef short short8 __attribute__((ext_vector_type(8)));   // 8 bf16 (4 VGPRs)
typedef float f32x4 __attribute__((ext_vector_type(4)));    // MFMA acc

// round-to-nearest-even f32 -> bf16
__device__ __forceinline__ ushort16 f2bf(float f) {
    uint32 u = __float_as_uint(f);
    u += 0x7fffu + ((u >> 16) & 1u);
    return (ushort16)(u >> 16);
}

// split f32 into bf16 hi + bf16 lo, f ~= hi + lo (error ~2^-16 rel)
__device__ __forceinline__ void splitbf(float f, unsigned short& hi, unsigned short& lo) {
    uint32 u = __float_as_uint(f);
    uint32 r = u + 0x7fffu + ((u >> 16) & 1u);
    hi = (unsigned short)(r >> 16);
    float hf = __uint_as_float((r >> 16) << 16);
    float res = f - hf;                    // exact (Sterbenz: same binade)
    uint32 v = __float_as_uint(res);
    lo = (unsigned short)((v + 0x7fffu + ((v >> 16) & 1u)) >> 16);
}

// ---------------- bucket histogram ----------------

__global__ __launch_bounds__(256)
void hist_bucket(const int* __restrict__ edst, int* __restrict__ bcnt, int E) {
    __shared__ int h[NBUCK];
    for (int b = threadIdx.x; b < NBUCK; b += 256) h[b] = 0;
    __syncthreads();
    for (int i = blockIdx.x * 256 + threadIdx.x; i < E; i += gridDim.x * 256)
        atomicAdd(&h[edst[i] >> 7], 1);
    __syncthreads();
    for (int b = threadIdx.x; b < NBUCK; b += 256) {
        int c = h[b];
        if (c) atomicAdd(&bcnt[b], c);
    }
}

// ---------------- bucket exclusive scan (one block) ----------------
// Also initializes fine-bucket cursors and coarse-group cursors (gcur[g] = bptr[64g]).

__global__ __launch_bounds__(256)
void bucket_scan(const int* __restrict__ bcnt, int* __restrict__ bptr,
                 int* __restrict__ cursor, int* __restrict__ gcur,
                 int* __restrict__ row_ptr, int E) {
    __shared__ int st[256];
    int tid = threadIdx.x;
    int v4[4];
    int s0 = 0;
#pragma unroll
    for (int k = 0; k < 4; k++) {
        int b = tid * 4 + k;
        v4[k] = (b < NBUCK) ? bcnt[b] : 0;
        s0 += v4[k];
    }
    st[tid] = s0;
    __syncthreads();
    for (int off = 1; off < 256; off <<= 1) {
        int t = (tid >= off) ? st[tid - off] : 0;
        __syncthreads();
        st[tid] += t;
        __syncthreads();
    }
    int run = st[tid] - s0;
    // thread 16g holds exclusive prefix of bucket 64g == group-g start
    if ((tid & 15) == 0 && (tid >> 4) < NCG) gcur[(tid >> 4) * CURSTRIDE] = run;
#pragma unroll
    for (int k = 0; k < 4; k++) {
        int b = tid * 4 + k;
        if (b < NBUCK) { bptr[b] = run; cursor[b * CURSTRIDE] = run; }
        run += v4[k];
    }
    if (tid == 255) bptr[NBUCK] = run;
    if (tid == 0) row_ptr[N_NODES] = E;
}

// ---------------- per-bucket counting sort -> row-sorted CSR (in place) ----------------
// 512 threads: latency-bound kernel, more waves/CU (24 vs 12) to hide LDS/atomic latency.

__global__ __launch_bounds__(512)
void bucket_to_csr(const int* __restrict__ bptr, int2* __restrict__ part,
                   int* __restrict__ row_ptr) {
    __shared__ int2 se[BCAP];
    __shared__ int rcnt[128];
    __shared__ int rcur[128];
    int tid = threadIdx.x;
    int b = blockIdx.x;
    int s = bptr[b], e = bptr[b + 1];
    int cnt = min(e - s, BCAP);

    if (tid < 128) rcnt[tid] = 0;
    __syncthreads();
    for (int j = tid; j < cnt; j += 512) {
        int2 p = part[s + j];
        se[j] = p;
        atomicAdd(&rcnt[p.x >> 17], 1);
    }
    __syncthreads();

    int v = (tid < 128) ? rcnt[tid] : 0;
    if (tid < 128) rcur[tid] = v;
    __syncthreads();
    for (int off = 1; off < 128; off <<= 1) {
        int t = 0;
        if (tid < 128 && tid >= off) t = rcur[tid - off];
        __syncthreads();
        if (tid < 128 && tid >= off) rcur[tid] += t;
        __syncthreads();
    }
    if (tid < 128) {
        int excl = rcur[tid] - v;
        rcur[tid] = excl;
        int row = b * 128 + tid;
        if (row < N_NODES) row_ptr[row] = s + excl;
    }
    __syncthreads();

    for (int j = tid; j < cnt; j += 512) {
        int2 p = se[j];
        int r = p.x >> 17;
        int pos = atomicAdd(&rcur[r], 1);
        part[s + pos] = make_int2(p.x & 0x1FFFF, p.y);
    }
}

// ---------------- weight split to MFMA-fragment-major layout (tiny, once) ----------------
// Layout: [kblk][nfrag][lane][8]  with  n = nfrag*16 + (lane&15), k = kblk*32 + (lane>>4)*8 + j

__global__ __launch_bounds__(256)
void splitw_kernel(const float* __restrict__ w1, const float* __restrict__ w2,
                   unsigned short* __restrict__ w1f_hi, unsigned short* __restrict__ w1f_lo,
                   unsigned short* __restrict__ w2f_hi, unsigned short* __restrict__ w2f_lo) {
    const int W1_SLOTS = (IN_DIM / 32) * (HIDDEN / 16) * 64;   // 4096
    const int W2_SLOTS = (HIDDEN / 32) * (OUT_DIM / 16) * 64;  // 1024
    int g = blockIdx.x * 256 + threadIdx.x;
    if (g < W1_SLOTS) {
        int lane = g & 63;
        int rest = g >> 6;
        int nfrag = rest & 7;              // HIDDEN/16 = 8
        int kblk = rest >> 3;
        int n = nfrag * 16 + (lane & 15);
        int k0 = kblk * 32 + (lane >> 4) * 8;
#pragma unroll
        for (int j = 0; j < 8; j++) {
            unsigned short h, l;
            splitbf(w1[(size_t)(k0 + j) * HIDDEN + n], h, l);
            w1f_hi[(size_t)g * 8 + j] = h;
            w1f_lo[(size_t)g * 8 + j] = l;
        }
    } else if (g < W1_SLOTS + W2_SLOTS) {
        int g2 = g - W1_SLOTS;
        int lane = g2 & 63;
        int rest = g2 >> 6;
        int nfrag = rest & 3;              // OUT_DIM/16 = 4
        int kblk = rest >> 2;
        int n = nfrag * 16 + (lane & 15);
        int k0 = kblk * 32 + (lane >> 4) * 8;
#pragma unroll
        for (int j = 0; j < 8; j++) {
            unsigned short h, l;
            splitbf(w2[(size_t)(k0 + j) * OUT_DIM + n], h, l);
            w2f_hi[(size_t)g2 * 8 + j] = h;
            w2f_lo[(size_t)g2 * 8 + j] = l;
        }
    }
}

// ---------------- MFMA GEMM body (device fn): C(bf16) = A(fp32) @ B, split-bf16 3-product ----

template <int K, int BN>
__device__ __forceinline__ void gemm_body(int bx, char* smem, const float* __restrict__ A,
                                          const unsigned short* __restrict__ Bf_hi,
                                          const unsigned short* __restrict__ Bf_lo,
                                          ushort16* __restrict__ C, int M) {
    constexpr int BM = 128, BK = 64;
    constexpr int NF = BN / 32;
    unsigned short* Ah = (unsigned short*)smem;                 // 16384 B
    unsigned short* Al = (unsigned short*)(smem + BM * BK * 2); // 16384 B

    int tid = threadIdx.x;
    int wid = tid >> 6, lane = tid & 63;
    int wr = wid >> 1, wc = wid & 1;
    int rowBase = bx * BM;
    int r = lane & 15, kg = lane >> 4;
    int swzmask = (lane & 7) << 4;

    f32x4 zero = {0.f, 0.f, 0.f, 0.f};
    f32x4 acc[4][NF];
#pragma unroll
    for (int m = 0; m < 4; m++)
#pragma unroll
        for (int n = 0; n < NF; n++) acc[m][n] = zero;

    int sk4 = (tid & 15) * 4;
    int sm0 = tid >> 4;

    for (int k0 = 0; k0 < K; k0 += BK) {
#pragma unroll
        for (int i = 0; i < 8; i++) {
            int m = sm0 + i * 16;
            int row = rowBase + m;
            float4 f = make_float4(0.f, 0.f, 0.f, 0.f);
            if (row < M) f = *(const float4*)(A + (size_t)row * K + k0 + sk4);
            ushort4 h, l;
            splitbf(f.x, h.x, l.x);
            splitbf(f.y, h.y, l.y);
            splitbf(f.z, h.z, l.z);
            splitbf(f.w, h.w, l.w);
            int bo = (m * BK + sk4) * 2;
            int swz = bo ^ ((m & 7) << 4);
            *(ushort4*)((char*)Ah + swz) = h;
            *(ushort4*)((char*)Al + swz) = l;
        }
        __syncthreads();

#pragma unroll
        for (int kk = 0; kk < BK / 32; kk++) {
            short8 ah[4], al[4];
            int abase = (wr * 64 + r) * (BK * 2) + kk * 64 + kg * 16;
#pragma unroll
            for (int m = 0; m < 4; m++) {
                int swz = (abase + m * (16 * BK * 2)) ^ swzmask;
                ah[m] = *(const short8*)((const char*)Ah + swz);
                al[m] = *(const short8*)((const char*)Al + swz);
            }
            short8 bh[NF], bl[NF];
            int kblk = (k0 >> 5) + kk;
#pragma unroll
            for (int n = 0; n < NF; n++) {
                int nf = wc * NF + n;
                size_t off = ((size_t)(kblk * (BN / 16) + nf) * 64 + lane) * 8;
                bh[n] = *(const short8*)(Bf_hi + off);
                bl[n] = *(const short8*)(Bf_lo + off);
            }
#pragma unroll
            for (int m = 0; m < 4; m++)
#pragma unroll
                for (int n = 0; n < NF; n++) {
                    acc[m][n] = __builtin_amdgcn_mfma_f32_16x16x32_bf16(ah[m], bh[n], acc[m][n], 0, 0, 0);
                    acc[m][n] = __builtin_amdgcn_mfma_f32_16x16x32_bf16(ah[m], bl[n], acc[m][n], 0, 0, 0);
                    acc[m][n] = __builtin_amdgcn_mfma_f32_16x16x32_bf16(al[m], bh[n], acc[m][n], 0, 0, 0);
                }
        }
        __syncthreads();
    }

#pragma unroll
    for (int m = 0; m < 4; m++) {
        int row0 = rowBase + wr * 64 + m * 16 + kg * 4;
#pragma unroll
        for (int j = 0; j < 4; j++) {
            int row = row0 + j;
            if (row < M) {
#pragma unroll
                for (int n = 0; n < NF; n++) {
                    int col = wc * (BN / 2) + n * 16 + r;
                    C[(size_t)row * BN + col] = f2bf(acc[m][n][j]);
                }
            }
        }
    }
}

// standalone GEMM kernel (layer 2)
template <int K, int BN>
__launch_bounds__(256)
__global__ void gemm_mfma(const float* __restrict__ A,
                          const unsigned short* __restrict__ Bf_hi,
                          const unsigned short* __restrict__ Bf_lo,
                          ushort16* __restrict__ C, int M) {
    __shared__ __align__(16) char smem[32768];
    gemm_body<K, BN>(blockIdx.x, smem, A, Bf_hi, Bf_lo, C, M);
}

// ---------------- fused: pass-1 coarse partition (blocks < NPB) + gemm1 (blocks >= NPB) ----
// Pass 1: partition edges into NCG=13 coarse groups (dst>>13). Runs ~236 edges = 1.9KB
// -> fully coalesced global writes. Payload: p.x = src | (dst&8191)<<17 ; p.y = val.

__launch_bounds__(256)
__global__ void partition_gemm1(const int* __restrict__ esrc, const int* __restrict__ edst,
                                const float* __restrict__ evals, int* __restrict__ gcur,
                                int2* __restrict__ part2, int E,
                                const float* __restrict__ A,
                                const unsigned short* __restrict__ w1f_hi,
                                const unsigned short* __restrict__ w1f_lo,
                                ushort16* __restrict__ pre1, int M) {
    __shared__ __align__(16) char smem[32768];
    if (blockIdx.x >= NPB) {
        gemm_body<IN_DIM, HIDDEN>(blockIdx.x - NPB, smem, A, w1f_hi, w1f_lo, pre1, M);
        return;
    }
    int2* sbp = (int2*)smem;                              // [0, 24576)
    unsigned char* sbg = (unsigned char*)(smem + 24576);  // [24576, 27648)
    int* hist = (int*)(smem + 27648);                     // 13
    int* lst  = (int*)(smem + 27712);                     // 13
    int* bpos = (int*)(smem + 27776);                     // 13

    int tid = threadIdx.x;
    long base = (long)blockIdx.x * CHUNK;
    int cnt = (int)min((long)CHUNK, (long)E - base);

    if (tid < NCG) hist[tid] = 0;
    __syncthreads();

    int d[NPT], sv[NPT]; float vv[NPT];
#pragma unroll
    for (int k = 0; k < NPT; k++) {
        int j = tid + k * 256;
        d[k] = -1;
        if (j < cnt) {
            d[k]  = edst[base + j];
            sv[k] = esrc[base + j];
            vv[k] = evals[base + j];
            atomicAdd(&hist[d[k] >> CGBITS], 1);
        }
    }
    __syncthreads();

    if (tid == 0) {
        int run = 0;
#pragma unroll
        for (int g = 0; g < NCG; g++) { lst[g] = run; run += hist[g]; }
    }
    __syncthreads();

    if (tid < NCG) {
        int c = hist[tid];
        int g = c ? atomicAdd(&gcur[tid * CURSTRIDE], c) : 0;
        bpos[tid] = g - lst[tid];
        hist[tid] = lst[tid];
    }
    __syncthreads();

#pragma unroll
    for (int k = 0; k < NPT; k++) {
        int j = tid + k * 256;
        if (j < cnt) {
            int dd = d[k], g = dd >> CGBITS;
            int pos = atomicAdd(&hist[g], 1);
            sbg[pos] = (unsigned char)g;
            sbp[pos] = make_int2(sv[k] | ((dd & 8191) << 17), __float_as_int(vv[k]));
        }
    }
    __syncthreads();

    for (int j = tid; j < cnt; j += 256)
        part2[bpos[sbg[j]] + j] = sbp[j];
}

// ---------------- pass 2: coarse group -> 64 fine buckets ----------------
// Block (g, c) handles chunk c of group g. Runs ~48 edges = 384B (near-coalesced).
// Output payload: p.x = src | (dst&127)<<17 (as consumed by bucket_to_csr).

__global__ __launch_bounds__(256)
void pass2_kernel(const int2* __restrict__ part2, const int* __restrict__ bptr,
                  int* __restrict__ cursor, int2* __restrict__ part) {
    __shared__ __align__(16) int2 sbp[CHUNK];          // 24576
    __shared__ unsigned char sbb[CHUNK];               // 3072
    __shared__ int hist[64], lst[64], bpos[64];
    int tid = threadIdx.x;
    int g = blockIdx.x / MAXCH;
    int c = blockIdx.x % MAXCH;
    int gs = bptr[min(64 * g, NBUCK)];
    int ge = bptr[min(64 * (g + 1), NBUCK)];
    int base = gs + c * CHUNK;
    if (base >= ge) return;
    int cnt = min(CHUNK, ge - base);
    int b0 = g * 64;                                   // first fine bucket of group

    if (tid < 64) hist[tid] = 0;
    __syncthreads();

    int lb[NPT]; int2 pp[NPT];
#pragma unroll
    for (int k = 0; k < NPT; k++) {
        int j = tid + k * 256;
        lb[k] = -1;
        if (j < cnt) {
            pp[k] = part2[base + j];
            int dst = (g << CGBITS) | ((uint32)pp[k].x >> 17);
            lb[k] = (dst >> 7) - b0;                   // 0..63
            atomicAdd(&hist[lb[k]], 1);
        }
    }
    __syncthreads();

    if (tid < 64) {                                    // single-wave scan over 64 buckets
        int cc = hist[tid];
        int sum = cc;
#pragma unroll
        for (int off = 1; off < 64; off <<= 1) {
            int up = __shfl_up(sum, off);
            if (tid >= off) sum += up;
        }
        lst[tid] = sum - cc;
    }
    __syncthreads();

    if (tid < 64) {
        int cc = hist[tid];
        int gp = cc ? atomicAdd(&cursor[(b0 + tid) * CURSTRIDE], cc) : 0;
        bpos[tid] = gp - lst[tid];
        hist[tid] = lst[tid];
    }
    __syncthreads();

#pragma unroll
    for (int k = 0; k < NPT; k++) {
        int j = tid + k * 256;
        if (j < cnt) {
            int b = lb[k];
            int pos = atomicAdd(&hist[b], 1);
            sbb[pos] = (unsigned char)b;
            int dst = (g << CGBITS) | ((uint32)pp[k].x >> 17);
            sbp[pos] = make_int2((pp[k].x & 0x1FFFF) | ((dst & 127) << 17), pp[k].y);
        }
    }
    __syncthreads();

    for (int j = tid; j < cnt; j += 256)
        part[bpos[sbb[j]] + j] = sbp[j];
}

// ---------------- SpMM: wave per dst row, multi-edge-per-gather, deep pipeline ----------------
// D=128: 8 gathers in flight (was 4 - VGPR 24 showed compiler kept <=2 outstanding).
// D=64: 4-deep (8-deep would waste slots on avg-32-edge rows).

template <int D, bool RELU>
__launch_bounds__(256)
__global__ void spmm_kernel(const ushort16* __restrict__ feat, const int2* __restrict__ csr_pair,
                            const int* __restrict__ row_ptr, float* __restrict__ out, int n) {
    constexpr int LPR = D * 2 / 16;      // lanes per row: 16 (D=128) or 8 (D=64)
    constexpr int EPG = 64 / LPR;        // edges per gather: 4 or 8
    constexpr int DEPTH = (D == 128) ? 8 : 4;
    int wid = threadIdx.x >> 6;
    int lane = threadIdx.x & 63;
    int row = blockIdx.x * 4 + wid;
    if (row >= n) return;
    int s = row_ptr[row], e = row_ptr[row + 1];

    int sub = lane / LPR;
    int slot = lane % LPR;
    const char* fbase = (const char*)feat + slot * 16;

    float acc[8];
#pragma unroll
    for (int j = 0; j < 8; j++) acc[j] = 0.f;

    for (int i = s; i < e; i += DEPTH * EPG) {
        int2 p[DEPTH]; float v[DEPTH]; uint4 u[DEPTH];
#pragma unroll
        for (int q = 0; q < DEPTH; q++) {
            int ii = i + q * EPG + sub;
            p[q] = csr_pair[min(ii, e - 1)];
            v[q] = (ii < e) ? __int_as_float(p[q].y) : 0.f;
        }
#pragma unroll
        for (int q = 0; q < DEPTH; q++)
            u[q] = *(const uint4*)(fbase + (size_t)p[q].x * (D * 2));
#pragma unroll
        for (int q = 0; q < DEPTH; q++) {
#pragma unroll
            for (int t = 0; t < 4; t++) {
                uint32 w = (&u[q].x)[t];
                acc[2 * t]     += v[q] * __uint_as_float(w << 16);
                acc[2 * t + 1] += v[q] * __uint_as_float(w & 0xffff0000u);
            }
        }
    }

#pragma unroll
    for (int m = LPR; m < 64; m <<= 1) {
#pragma unroll
        for (int j = 0; j < 8; j++) acc[j] += __shfl_xor(acc[j], m);
    }

    if (RELU) {
#pragma unroll
        for (int j = 0; j < 8; j++) acc[j] = acc[j] > 0.f ? acc[j] : 0.f;
    }

    if (lane < LPR) {
        float4* o = (float4*)(out + (size_t)row * D + slot * 8);
        o[0] = make_float4(acc[0], acc[1], acc[2], acc[3]);
        o[1] = make_float4(acc[4], acc[5], acc[6], acc[7]);
    }
}

// ---------------- launch ----------------

extern "C" void kernel_launch(void* const* d_in, const int* in_sizes, int n_in,
                              void* d_out, int out_size, void* d_ws, size_t ws_size,
                              hipStream_t stream) {
    const float* x    = (const float*)d_in[0];
    const float* adj  = (const float*)d_in[1];
    const float* w1   = (const float*)d_in[2];
    const float* w2   = (const float*)d_in[3];
    const int*   esrc = (const int*)d_in[4];
    const int*   edst = (const int*)d_in[5];
    float* out = (float*)d_out;

    const int N = N_NODES;
    const int E = N_EDGES;

    char* ws = (char*)d_ws;
    size_t off = 0;
    auto take = [&](size_t bytes) -> char* {
        char* p = ws + off;
        off = (off + bytes + 255) & ~(size_t)255;
        return p;
    };
    int*      bcnt    = (int*)take((size_t)NBUCK * 4);
    int*      bptr    = (int*)take((size_t)(NBUCK + 1) * 4);
    int*      cursor  = (int*)take((size_t)NBUCK * CURSTRIDE * 4);   // fine-bucket cursors
    int*      gcur    = (int*)take((size_t)NCG * CURSTRIDE * 4);     // coarse-group cursors
    int*      row_ptr = (int*)take((size_t)(N + 1) * 4);
    int2*     part    = (int2*)take((size_t)E * 8);          // becomes row-sorted CSR
    int2*     part2   = (int2*)take((size_t)E * 8);          // coarse-grouped temp
    ushort16* pre1    = (ushort16*)take((size_t)N * HIDDEN * 2);   // bf16
    ushort16* pre2    = (ushort16*)take((size_t)N * OUT_DIM * 2);  // bf16
    float*    h       = (float*)take((size_t)N * HIDDEN * 4);      // fp32
    unsigned short* w1f_hi = (unsigned short*)take((size_t)HIDDEN * IN_DIM * 2);
    unsigned short* w1f_lo = (unsigned short*)take((size_t)HIDDEN * IN_DIM * 2);
    unsigned short* w2f_hi = (unsigned short*)take((size_t)OUT_DIM * HIDDEN * 2);
    unsigned short* w2f_lo = (unsigned short*)take((size_t)OUT_DIM * HIDDEN * 2);

    // weight split to fragment-major (tiny)
    splitw_kernel<<<20, 256, 0, stream>>>(w1, w2, w1f_hi, w1f_lo, w2f_hi, w2f_lo);

    // CSR build prologue
    hipMemsetAsync(bcnt, 0, (size_t)NBUCK * 4, stream);
    hist_bucket<<<1024, 256, 0, stream>>>(edst, bcnt, E);
    bucket_scan<<<1, 256, 0, stream>>>(bcnt, bptr, cursor, gcur, row_ptr, E);

    // Fused: pass-1 coarse partition (1042 blocks) + gemm1 pre1 = bf16(X@W1) (782 blocks)
    partition_gemm1<<<NPB + (N_NODES + 127) / 128, 256, 0, stream>>>(
        esrc, edst, adj, gcur, part2, E, x, w1f_hi, w1f_lo, pre1, N);

    // pass 2: coarse groups -> fine buckets
    pass2_kernel<<<NCG * MAXCH, 256, 0, stream>>>(part2, bptr, cursor, part);

    bucket_to_csr<<<NBUCK, 512, 0, stream>>>(bptr, part, row_ptr);

    // Layer 1 SpMM: h = relu(A @ pre1) in fp32
    spmm_kernel<HIDDEN, true><<<(N + 3) / 4, 256, 0, stream>>>(pre1, part, row_ptr, h, N);

    // Layer 2: pre2 = bf16(h@W2) via MFMA ; out = A @ pre2 in fp32
    gemm_mfma<HIDDEN, OUT_DIM><<<(N + 127) / 128, 256, 0, stream>>>(h, w2f_hi, w2f_lo, pre2, N);
    spmm_kernel<OUT_DIM, false><<<(N + 3) / 4, 256, 0, stream>>>(pre2, part, row_ptr, out, N);
}